// Round 2
// baseline (195.525 us; speedup 1.0000x reference)
//
#include <hip/hip_runtime.h>
#include <hip/hip_bf16.h>
#include <stdint.h>

// SelfAttention B=2,T=2048,C=1024,H=16,hd=64. Inputs fp32, output fp32.
// R13: causal PAIRING. Each attn block owns q-tiles (X, 31-X) serially:
// work = (X+1)+(32-X) = 33 tiles for EVERY block, independent of the
// dispatch mapping (R12's sum-balance still left ragged per-stream tails;
// measured occupancy 22%). Grid (16,32) = 512 blocks = uniform 2 blk/CU,
// 8 waves/CU, all streams finish together. Prefetch chains across the
// pass boundary (last iter of pass 0 prefetches pass 1's tile 0).
// Keeps: exact diagonal j-skip, builtin exp2, setprio around MFMA.

typedef __bf16 bf16_t;
typedef __attribute__((ext_vector_type(8))) __bf16 bf16x8;
typedef __attribute__((ext_vector_type(4))) __bf16 bf16x4;
typedef __attribute__((ext_vector_type(4))) short short4v;
typedef __attribute__((ext_vector_type(4))) float f32x4;

static_assert(sizeof(bf16x8) == 16, "bf16x8 must be 16B");

#if defined(__has_builtin)
#if __has_builtin(__builtin_amdgcn_mfma_f32_16x16x16bf16_1k)
#define HAVE_MFMA16 1
#endif
#if __has_builtin(__builtin_amdgcn_exp2f)
#define EXP2F(x) __builtin_amdgcn_exp2f(x)
#endif
#endif
#ifndef HAVE_MFMA16
#define HAVE_MFMA16 0
#endif
#ifndef EXP2F
#define EXP2F(x) exp2f(x)
#endif

// async global->LDS, 16B/lane. LDS dest = wave-uniform base + lane*16.
__device__ inline void async_copy16(const bf16_t* gsrc, bf16_t* lds_dst) {
  __builtin_amdgcn_global_load_lds(
      (const __attribute__((address_space(1))) uint32_t*)(const void*)gsrc,
      (__attribute__((address_space(3))) uint32_t*)(void*)lds_dst,
      16, 0, 0);
}

// ---------------------------------------------------------------------------
// Merged prep: blocks [0,2048) convx; [2048,5120) transpose w_qkv;
// [5120,6144) transpose w_out.
// ---------------------------------------------------------------------------
__global__ __launch_bounds__(256) void prep_kernel(
    const float* __restrict__ x, const float* __restrict__ wq,
    const float* __restrict__ wo, bf16_t* __restrict__ xb,
    bf16_t* __restrict__ wqkvT, bf16_t* __restrict__ woutT) {
  __shared__ bf16_t tile[32][33];
  const int bid = blockIdx.x;
  if (bid < 2048) {
    const int i = bid * 256 + threadIdx.x;  // < 524288
    const float4* s = (const float4*)x;
    float4 a = s[i * 2], b = s[i * 2 + 1];
    bf16x8 o;
    o[0] = (bf16_t)a.x; o[1] = (bf16_t)a.y; o[2] = (bf16_t)a.z; o[3] = (bf16_t)a.w;
    o[4] = (bf16_t)b.x; o[5] = (bf16_t)b.y; o[6] = (bf16_t)b.z; o[7] = (bf16_t)b.w;
    ((bf16x8*)xb)[i] = o;
    return;
  }
  const bool isq = bid < 5120;
  const int id = isq ? bid - 2048 : bid - 5120;
  const int C = isq ? 3072 : 1024;
  const int R = 1024;
  const int nbx = isq ? 96 : 32;
  const float* in = isq ? wq : wo;
  bf16_t* out = isq ? wqkvT : woutT;
  const int c0 = (id % nbx) * 32, r0 = (id / nbx) * 32;
  const int tx = threadIdx.x & 31;
  const int ty = threadIdx.x >> 5;
#pragma unroll
  for (int i = 0; i < 4; i++) {
    int r = ty + i * 8;
    tile[r][tx] = (bf16_t)in[(size_t)(r0 + r) * C + c0 + tx];
  }
  __syncthreads();
#pragma unroll
  for (int i = 0; i < 4; i++) {
    int r = ty + i * 8;
    out[(size_t)(c0 + r) * R + r0 + tx] = tile[tx][r];
  }
}

// ---------------------------------------------------------------------------
// C[M,N] = A[M,K] @ Bt[N,K]^T + bias[N]. bf16 in; OUT_F32 selects store type.
// BM=BN=128, BK=32, 4 waves 2x2. m97-style global_load_lds staging. (R10)
// ---------------------------------------------------------------------------
template <bool OUT_F32>
__global__ __launch_bounds__(256) void gemm_bt_kernel(
    const bf16_t* __restrict__ A, const bf16_t* __restrict__ Bt,
    const float* __restrict__ bias, void* __restrict__ Cv, int M, int N,
    int K) {
  __shared__ __align__(16) bf16_t sA[128 * 32];
  __shared__ __align__(16) bf16_t sB[128 * 32];
  const int tid = threadIdx.x;
  const int wave = tid >> 6, lane = tid & 63;
  const int quad = lane >> 4, l16 = lane & 15;
  const int wm = (wave >> 1) * 64, wn = (wave & 1) * 64;
  const int bm = blockIdx.y * 128, bn = blockIdx.x * 128;

  const int srow = wave * 16 + (lane >> 2);
  const int skk = (lane & 3) * 8;
  const bf16_t* gA = A + (size_t)(bm + srow) * K + skk;
  const bf16_t* gB = Bt + (size_t)(bn + srow) * K + skk;
  bf16_t* lA = sA + wave * 512;
  bf16_t* lB = sB + wave * 512;

  f32x4 acc[4][4] = {};

  for (int k0 = 0; k0 < K; k0 += 32) {
    __syncthreads();
    async_copy16(gA + k0, lA);
    async_copy16(gA + (size_t)64 * K + k0, lA + 2048);
    async_copy16(gB + k0, lB);
    async_copy16(gB + (size_t)64 * K + k0, lB + 2048);
    __syncthreads();

    bf16x8 af[4], bfr[4];
#pragma unroll
    for (int i = 0; i < 4; i++)
      af[i] = *(const bf16x8*)&sA[(wm + i * 16 + l16) * 32 + quad * 8];
#pragma unroll
    for (int j = 0; j < 4; j++)
      bfr[j] = *(const bf16x8*)&sB[(wn + j * 16 + l16) * 32 + quad * 8];
#pragma unroll
    for (int i = 0; i < 4; i++)
#pragma unroll
      for (int j = 0; j < 4; j++)
        acc[i][j] = __builtin_amdgcn_mfma_f32_16x16x32_bf16(af[i], bfr[j],
                                                            acc[i][j], 0, 0, 0);
  }

#pragma unroll
  for (int j = 0; j < 4; j++) {
    const int col = bn + wn + j * 16 + l16;
    const float bv = bias[col];
#pragma unroll
    for (int i = 0; i < 4; i++) {
#pragma unroll
      for (int r = 0; r < 4; r++) {
        const int row = bm + wm + i * 16 + quad * 4 + r;
        const float v = acc[i][j][r] + bv;
        if (OUT_F32)
          ((float*)Cv)[(size_t)row * N + col] = v;
        else
          ((bf16_t*)Cv)[(size_t)row * N + col] = (bf16_t)v;
      }
    }
  }
}

#if HAVE_MFMA16
// ---------------------------------------------------------------------------
// R13 attention: S^T = K@Q^T (16x16x32), P stays in registers as the K=16
// MFMA A-fragment; O += P@V via mfma_f32_16x16x16_bf16. Double-buffered
// sK/sVt, ONE barrier per 64-key tile. Fixed-M softmax.
// sK : (t,d) at t*64 + (((d>>3) ^ (t&7))<<3) + (d&7)        [8 KB/buf]
// sVt: (d,t) at d*64 + (((t>>2) ^ (d&15))<<2) + (t&3)       [8 KB/buf]
// Block owns q-tile pair (bx, 31-bx): exactly 33 tiles per block.
// ---------------------------------------------------------------------------
__global__ __launch_bounds__(256, 4) void attn_kernel(
    const bf16_t* __restrict__ qkv, bf16_t* __restrict__ Y) {
  constexpr int T = 2048, C3 = 3072;
  constexpr float CSC = 0.18033688f;  // 0.125 * log2(e)
  constexpr float MB = 20.0f;
  __shared__ __align__(16) bf16_t sK[2][64 * 64];
  __shared__ __align__(16) bf16_t sVt[2][64 * 64];

  const int tid = threadIdx.x;
  const int wave = tid >> 6, lane = tid & 63;
  const int quad = lane >> 4, l16 = lane & 15;
  const int bh = blockIdx.y;
  const int b = bh >> 4, h = bh & 15;
  const size_t base = (size_t)b * T * C3 + (size_t)h * 64;

  // K staging: (t = tid>>2 key row, seg = tid&3)
  const int t = tid >> 2, seg = tid & 3;
  const bf16_t* gK = &qkv[base + (size_t)t * C3 + 1024 + seg * 16];
  // V staging: (kq = tid>>4 key-quad, dq = tid&15 d-quad)
  const int kq = tid >> 4, dq = tid & 15;
  const bf16_t* gV = &qkv[base + (size_t)(4 * kq) * C3 + 2048 + dq * 4];

  // prime tile-0 prefetch (shared across the pass boundary)
  bf16x8 kr0 = *(const bf16x8*)gK;
  bf16x8 kr1 = *(const bf16x8*)(gK + 8);
  bf16x4 vA0 = *(const bf16x4*)gV;
  bf16x4 vA1 = *(const bf16x4*)(gV + C3);
  bf16x4 vA2 = *(const bf16x4*)(gV + 2 * C3);
  bf16x4 vA3 = *(const bf16x4*)(gV + 3 * C3);

#pragma unroll 1
  for (int qs = 0; qs < 2; qs++) {
    const int X = qs ? (31 - (int)blockIdx.x) : (int)blockIdx.x;
    const int q0 = X * 64;
    // Q as B-operand: lane n=l16=query, k = quad*8+j
    const int qrow = q0 + wave * 16 + l16;
    const bf16x8 qf0 =
        *(const bf16x8*)&qkv[base + (size_t)qrow * C3 + quad * 8];
    const bf16x8 qf1 =
        *(const bf16x8*)&qkv[base + (size_t)qrow * C3 + 32 + quad * 8];

    f32x4 o[4] = {};   // lane holds rows (query) quad*4+r, col d = n16*16+l16
    float l_acc = 0.f; // per-lane partial sum for query l16 over quad's keys
    const int ktiles = X + 1;

    // pass boundary: previous pass's last compute may still read buf 0
    if (qs) __syncthreads();

    for (int kt = 0; kt < ktiles; kt++) {
      const int p = kt & 1;
      // stage K (2 b128, swizzled) and V (4 b64, key-quad granules)
      *(bf16x8*)&sK[p][t * 64 + (((2 * seg + 0) ^ (t & 7)) << 3)] = kr0;
      *(bf16x8*)&sK[p][t * 64 + (((2 * seg + 1) ^ (t & 7)) << 3)] = kr1;
#pragma unroll
      for (int i = 0; i < 4; i++) {
        const int d = dq * 4 + i;
        bf16x4 w;
        w[0] = vA0[i]; w[1] = vA1[i]; w[2] = vA2[i]; w[3] = vA3[i];
        *(bf16x4*)&sVt[p][d * 64 + ((kq ^ (d & 15)) << 2)] = w;
      }
      // prefetch next tile; on pass-0's last iter, prefetch pass-1 tile 0
      const int nkt = (kt + 1 < ktiles) ? (kt + 1) : (qs ? -1 : 0);
      if (nkt >= 0) {
        const size_t off = (size_t)nkt * 64 * C3;
        kr0 = *(const bf16x8*)(gK + off);
        kr1 = *(const bf16x8*)(gK + off + 8);
        vA0 = *(const bf16x4*)(gV + off);
        vA1 = *(const bf16x4*)(gV + off + C3);
        vA2 = *(const bf16x4*)(gV + off + 2 * C3);
        vA3 = *(const bf16x4*)(gV + off + 3 * C3);
      }
      __syncthreads();  // single barrier: buf p visible; buf 1-p free

      const bool last = (kt == ktiles - 1);
      const int jmax = last ? wave : 3;  // exact causal subtile skip
#pragma unroll
      for (int j = 0; j < 4; j++) {
        if (j > jmax) continue;  // wave-uniform; P would be all-zero
        // S^T j-tile: A = K-frag (lane m=l16 -> key j*16+l16), B = Q-frag
        const int trow = j * 16 + l16;
        bf16x8 kf0 =
            *(const bf16x8*)&sK[p][trow * 64 + ((quad ^ (trow & 7)) << 3)];
        bf16x8 kf1 =
            *(const bf16x8*)&sK[p][trow * 64 + (((4 + quad) ^ (trow & 7)) << 3)];
        f32x4 s2 = {};
        __builtin_amdgcn_s_setprio(1);
        s2 = __builtin_amdgcn_mfma_f32_16x16x32_bf16(kf0, qf0, s2, 0, 0, 0);
        s2 = __builtin_amdgcn_mfma_f32_16x16x32_bf16(kf1, qf1, s2, 0, 0, 0);
        __builtin_amdgcn_s_setprio(0);
        // S^T D-layout: lane col=l16=query, rows quad*4+r = key j*16+quad*4+r
        const bool diag = last && (j == wave);
#pragma unroll
        for (int r = 0; r < 4; r++) {
          float pv = EXP2F(fmaf(s2[r], CSC, -MB));
          if (diag && (quad * 4 + r > l16)) pv = 0.f;
          s2[r] = pv;
          l_acc += pv;
        }
        // C-regs ARE the K=16 A-fragment: lane m=l16=query, k=quad*4+r
        bf16x4 pb;
        pb[0] = (bf16_t)s2[0]; pb[1] = (bf16_t)s2[1];
        pb[2] = (bf16_t)s2[2]; pb[3] = (bf16_t)s2[3];
        union { bf16x4 bv; short4v sv; } u;
        u.bv = pb;
        const short4v pa = u.sv;
        __builtin_amdgcn_s_setprio(1);
#pragma unroll
        for (int n16 = 0; n16 < 4; n16++) {
          const int d = n16 * 16 + l16;
          const short4v vf = *(const short4v*)&sVt[p][d * 64 +
                                                      (((j * 4 + quad) ^
                                                        (d & 15))
                                                       << 2)];
          o[n16] = __builtin_amdgcn_mfma_f32_16x16x16bf16_1k(pa, vf, o[n16],
                                                             0, 0, 0);
        }
        __builtin_amdgcn_s_setprio(0);
      }
    }

    // epilogue: complete l across quads (2 shuffles), redistribute, store
    l_acc += __shfl_xor(l_acc, 16);
    l_acc += __shfl_xor(l_acc, 32);
#pragma unroll
    for (int r = 0; r < 4; r++) {
      const float lr = __shfl(l_acc, quad * 4 + r);
      const float inv = 1.0f / lr;
      const int row = q0 + wave * 16 + quad * 4 + r;
#pragma unroll
      for (int n16 = 0; n16 < 4; n16++)
        Y[((size_t)b * T + row) * 1024 + h * 64 + n16 * 16 + l16] =
            (bf16_t)(o[n16][r] * inv);
    }
  }
}
#else
// ---------------------------------------------------------------------------
// Fallback = R10 attention (sP round-trip), with the same pairing.
// ---------------------------------------------------------------------------
__global__ __launch_bounds__(256, 4) void attn_kernel(
    const bf16_t* __restrict__ qkv, bf16_t* __restrict__ Y) {
  constexpr int T = 2048, C3 = 3072;
  constexpr float CSC = 0.18033688f;
  constexpr float MB = 20.0f;
  __shared__ __align__(16) bf16_t sK[64 * 64];
  __shared__ __align__(16) bf16_t sVt[64 * 64];
  __shared__ __align__(16) bf16_t sP[4][16 * 64];

  const int tid = threadIdx.x;
  const int wave = tid >> 6, lane = tid & 63;
  const int quad = lane >> 4, l16 = lane & 15;
  const int bh = blockIdx.y;
  const int b = bh >> 4, h = bh & 15;
  const size_t base = (size_t)b * T * C3 + (size_t)h * 64;

  const int t = tid >> 2, seg = tid & 3;
  const int tk = t & 7, tg3 = t >> 3;
  const bf16_t* gK = &qkv[base + (size_t)t * C3 + 1024 + seg * 16];
  const bf16_t* gV = &qkv[base + (size_t)t * C3 + 2048 + seg * 16];

#pragma unroll 1
  for (int qs = 0; qs < 2; qs++) {
    const int X = qs ? (31 - (int)blockIdx.x) : (int)blockIdx.x;
    const int q0 = X * 64;
    const int qrow = q0 + wave * 16 + l16;
    const bf16x8 qf0 =
        *(const bf16x8*)&qkv[base + (size_t)qrow * C3 + quad * 8];
    const bf16x8 qf1 =
        *(const bf16x8*)&qkv[base + (size_t)qrow * C3 + 32 + quad * 8];

    f32x4 o[4] = {};
    float l_i[4] = {0.f, 0.f, 0.f, 0.f};
    const int ktiles = X + 1;

    bf16x8 kr0 = *(const bf16x8*)gK;
    bf16x8 kr1 = *(const bf16x8*)(gK + 8);
    bf16x8 vr0 = *(const bf16x8*)gV;
    bf16x8 vr1 = *(const bf16x8*)(gV + 8);

    for (int kt = 0; kt < ktiles; kt++) {
      __syncthreads();
      *(bf16x8*)&sK[t * 64 + (((2 * seg + 0) ^ tk) << 3)] = kr0;
      *(bf16x8*)&sK[t * 64 + (((2 * seg + 1) ^ tk) << 3)] = kr1;
#pragma unroll
      for (int i = 0; i < 8; i++) {
        const int d = seg * 16 + i;
        sVt[d * 64 + ((tg3 ^ (d >> 3)) << 3) + (t & 7)] = vr0[i];
      }
#pragma unroll
      for (int i = 0; i < 8; i++) {
        const int d = seg * 16 + 8 + i;
        sVt[d * 64 + ((tg3 ^ (d >> 3)) << 3) + (t & 7)] = vr1[i];
      }
      __syncthreads();

      if (kt + 1 < ktiles) {
        const size_t off = (size_t)(kt + 1) * 64 * C3;
        kr0 = *(const bf16x8*)(gK + off);
        kr1 = *(const bf16x8*)(gK + off + 8);
        vr0 = *(const bf16x8*)(gV + off);
        vr1 = *(const bf16x8*)(gV + off + 8);
      }

      f32x4 s[4] = {};
#pragma unroll
      for (int j = 0; j < 4; j++) {
        const int kkey = l16 & 7;
        bf16x8 kf0 =
            *(const bf16x8*)&sK[(j * 16 + l16) * 64 + ((quad ^ kkey) << 3)];
        bf16x8 kf1 =
            *(const bf16x8*)&sK[(j * 16 + l16) * 64 +
                                (((4 + quad) ^ kkey) << 3)];
        s[j] = __builtin_amdgcn_mfma_f32_16x16x32_bf16(qf0, kf0, s[j], 0, 0, 0);
        s[j] = __builtin_amdgcn_mfma_f32_16x16x32_bf16(qf1, kf1, s[j], 0, 0, 0);
      }

#pragma unroll
      for (int j = 0; j < 4; j++)
#pragma unroll
        for (int r = 0; r < 4; r++) s[j][r] = EXP2F(fmaf(s[j][r], CSC, -MB));
      if (kt == ktiles - 1) {
        const int k0 = kt * 64;
#pragma unroll
        for (int j = 0; j < 4; j++) {
          const int kcol = k0 + j * 16 + l16;
#pragma unroll
          for (int r = 0; r < 4; r++)
            if (kcol > q0 + wave * 16 + quad * 4 + r) s[j][r] = 0.f;
        }
      }
#pragma unroll
      for (int j = 0; j < 4; j++)
#pragma unroll
        for (int r = 0; r < 4; r++) l_i[r] += s[j][r];

      bf16_t* sp = &sP[wave][0];
#pragma unroll
      for (int j = 0; j < 4; j++)
#pragma unroll
        for (int r = 0; r < 4; r++) {
          const int m = quad * 4 + r;
          const int kw = (m + (m >> 3)) & 7;
          sp[m * 64 + ((((2 * j + (l16 >> 3)) ^ kw)) << 3) + (l16 & 7)] =
              (bf16_t)s[j][r];
        }

      const int kap = (l16 + (l16 >> 3)) & 7;
#pragma unroll
      for (int s2 = 0; s2 < 2; s2++) {
        bf16x8 pf =
            *(const bf16x8*)&sp[l16 * 64 + (((4 * s2 + quad) ^ kap) << 3)];
#pragma unroll
        for (int j = 0; j < 4; j++) {
          const int d = j * 16 + l16;
          bf16x8 vf =
              *(const bf16x8*)&sVt[d * 64 +
                                   (((4 * s2 + quad) ^ (d >> 3)) << 3)];
          o[j] = __builtin_amdgcn_mfma_f32_16x16x32_bf16(pf, vf, o[j], 0, 0, 0);
        }
      }
    }

#pragma unroll
    for (int r = 0; r < 4; r++) {
      float l = l_i[r];
#pragma unroll
      for (int off = 1; off < 16; off <<= 1) l += __shfl_xor(l, off);
      const float inv = 1.0f / l;
      const int row = q0 + wave * 16 + quad * 4 + r;
#pragma unroll
      for (int j = 0; j < 4; j++)
        Y[((size_t)b * T + row) * 1024 + h * 64 + j * 16 + l16] =
            (bf16_t)(o[j][r] * inv);
    }
  }
}
#endif

// ---------------------------------------------------------------------------
extern "C" void kernel_launch(void* const* d_in, const int* in_sizes, int n_in,
                              void* d_out, int out_size, void* d_ws,
                              size_t ws_size, hipStream_t stream) {
  const float* x = nullptr;
  const float* w_qkv = nullptr;
  const float* b_qkv = nullptr;
  const float* w_out = nullptr;
  const float* b_out = nullptr;
  for (int i = 0; i < n_in; i++) {
    switch (in_sizes[i]) {
      case 4194304: x = (const float*)d_in[i]; break;
      case 3145728: w_qkv = (const float*)d_in[i]; break;
      case 3072:    b_qkv = (const float*)d_in[i]; break;
      case 1048576: w_out = (const float*)d_in[i]; break;
      case 1024:    b_out = (const float*)d_in[i]; break;
      default: break;
    }
  }
  float* out = (float*)d_out;  // FP32 output

  bf16_t* xb = (bf16_t*)d_ws;
  bf16_t* wqkvT = xb + (size_t)4194304;
  bf16_t* woutT = wqkvT + (size_t)3145728;
  bf16_t* qkv = woutT + (size_t)1048576;
  bf16_t* Y = qkv + (size_t)12582912;

  prep_kernel<<<6144, 256, 0, stream>>>(x, w_qkv, w_out, xb, wqkvT, woutT);
  gemm_bt_kernel<false><<<dim3(24, 32), 256, 0, stream>>>(
      xb, wqkvT, b_qkv, (void*)qkv, 4096, 3072, 1024);
  attn_kernel<<<dim3(16, 32), 256, 0, stream>>>(qkv, Y);
  gemm_bt_kernel<true><<<dim3(8, 32), 256, 0, stream>>>(
      Y, woutT, b_out, (void*)out, 4096, 1024, 1024);
}

// Round 3
// 190.997 us; speedup vs baseline: 1.0237x; 1.0237x over previous
//
#include <hip/hip_runtime.h>
#include <hip/hip_bf16.h>
#include <stdint.h>

// SelfAttention B=2,T=2048,C=1024,H=16,hd=64. Inputs fp32, output fp32.
// R14: revert R13 pairing (FETCH doubled 62->120MB: desync'd key walks broke
// L2 sharing; occupancy halved). Back to R12 remap (grid 32x32, per-CU
// sum(X)==62, lockstep key walk from tile 0 => L2-shared K/V stream).
// New: (1) branchless hot tiles — diagonal tile hoisted out of the k-loop,
// so the 4 j-subtile chains have no runtime guards and can interleave;
// (2) f32x4 l-accumulator (4 parallel chains vs 16-deep serial add).
// Keeps: exact diagonal j-skip (in hoisted tail), builtin exp2, setprio.

typedef __bf16 bf16_t;
typedef __attribute__((ext_vector_type(8))) __bf16 bf16x8;
typedef __attribute__((ext_vector_type(4))) __bf16 bf16x4;
typedef __attribute__((ext_vector_type(4))) short short4v;
typedef __attribute__((ext_vector_type(4))) float f32x4;

static_assert(sizeof(bf16x8) == 16, "bf16x8 must be 16B");

#if defined(__has_builtin)
#if __has_builtin(__builtin_amdgcn_mfma_f32_16x16x16bf16_1k)
#define HAVE_MFMA16 1
#endif
#if __has_builtin(__builtin_amdgcn_exp2f)
#define EXP2F(x) __builtin_amdgcn_exp2f(x)
#endif
#endif
#ifndef HAVE_MFMA16
#define HAVE_MFMA16 0
#endif
#ifndef EXP2F
#define EXP2F(x) exp2f(x)
#endif

// async global->LDS, 16B/lane. LDS dest = wave-uniform base + lane*16.
__device__ inline void async_copy16(const bf16_t* gsrc, bf16_t* lds_dst) {
  __builtin_amdgcn_global_load_lds(
      (const __attribute__((address_space(1))) uint32_t*)(const void*)gsrc,
      (__attribute__((address_space(3))) uint32_t*)(void*)lds_dst,
      16, 0, 0);
}

// ---------------------------------------------------------------------------
// Merged prep: blocks [0,2048) convx; [2048,5120) transpose w_qkv;
// [5120,6144) transpose w_out.
// ---------------------------------------------------------------------------
__global__ __launch_bounds__(256) void prep_kernel(
    const float* __restrict__ x, const float* __restrict__ wq,
    const float* __restrict__ wo, bf16_t* __restrict__ xb,
    bf16_t* __restrict__ wqkvT, bf16_t* __restrict__ woutT) {
  __shared__ bf16_t tile[32][33];
  const int bid = blockIdx.x;
  if (bid < 2048) {
    const int i = bid * 256 + threadIdx.x;  // < 524288
    const float4* s = (const float4*)x;
    float4 a = s[i * 2], b = s[i * 2 + 1];
    bf16x8 o;
    o[0] = (bf16_t)a.x; o[1] = (bf16_t)a.y; o[2] = (bf16_t)a.z; o[3] = (bf16_t)a.w;
    o[4] = (bf16_t)b.x; o[5] = (bf16_t)b.y; o[6] = (bf16_t)b.z; o[7] = (bf16_t)b.w;
    ((bf16x8*)xb)[i] = o;
    return;
  }
  const bool isq = bid < 5120;
  const int id = isq ? bid - 2048 : bid - 5120;
  const int C = isq ? 3072 : 1024;
  const int R = 1024;
  const int nbx = isq ? 96 : 32;
  const float* in = isq ? wq : wo;
  bf16_t* out = isq ? wqkvT : woutT;
  const int c0 = (id % nbx) * 32, r0 = (id / nbx) * 32;
  const int tx = threadIdx.x & 31;
  const int ty = threadIdx.x >> 5;
#pragma unroll
  for (int i = 0; i < 4; i++) {
    int r = ty + i * 8;
    tile[r][tx] = (bf16_t)in[(size_t)(r0 + r) * C + c0 + tx];
  }
  __syncthreads();
#pragma unroll
  for (int i = 0; i < 4; i++) {
    int r = ty + i * 8;
    out[(size_t)(c0 + r) * R + r0 + tx] = tile[tx][r];
  }
}

// ---------------------------------------------------------------------------
// C[M,N] = A[M,K] @ Bt[N,K]^T + bias[N]. bf16 in; OUT_F32 selects store type.
// BM=BN=128, BK=32, 4 waves 2x2. m97-style global_load_lds staging. (R10)
// ---------------------------------------------------------------------------
template <bool OUT_F32>
__global__ __launch_bounds__(256) void gemm_bt_kernel(
    const bf16_t* __restrict__ A, const bf16_t* __restrict__ Bt,
    const float* __restrict__ bias, void* __restrict__ Cv, int M, int N,
    int K) {
  __shared__ __align__(16) bf16_t sA[128 * 32];
  __shared__ __align__(16) bf16_t sB[128 * 32];
  const int tid = threadIdx.x;
  const int wave = tid >> 6, lane = tid & 63;
  const int quad = lane >> 4, l16 = lane & 15;
  const int wm = (wave >> 1) * 64, wn = (wave & 1) * 64;
  const int bm = blockIdx.y * 128, bn = blockIdx.x * 128;

  const int srow = wave * 16 + (lane >> 2);
  const int skk = (lane & 3) * 8;
  const bf16_t* gA = A + (size_t)(bm + srow) * K + skk;
  const bf16_t* gB = Bt + (size_t)(bn + srow) * K + skk;
  bf16_t* lA = sA + wave * 512;
  bf16_t* lB = sB + wave * 512;

  f32x4 acc[4][4] = {};

  for (int k0 = 0; k0 < K; k0 += 32) {
    __syncthreads();
    async_copy16(gA + k0, lA);
    async_copy16(gA + (size_t)64 * K + k0, lA + 2048);
    async_copy16(gB + k0, lB);
    async_copy16(gB + (size_t)64 * K + k0, lB + 2048);
    __syncthreads();

    bf16x8 af[4], bfr[4];
#pragma unroll
    for (int i = 0; i < 4; i++)
      af[i] = *(const bf16x8*)&sA[(wm + i * 16 + l16) * 32 + quad * 8];
#pragma unroll
    for (int j = 0; j < 4; j++)
      bfr[j] = *(const bf16x8*)&sB[(wn + j * 16 + l16) * 32 + quad * 8];
#pragma unroll
    for (int i = 0; i < 4; i++)
#pragma unroll
      for (int j = 0; j < 4; j++)
        acc[i][j] = __builtin_amdgcn_mfma_f32_16x16x32_bf16(af[i], bfr[j],
                                                            acc[i][j], 0, 0, 0);
  }

#pragma unroll
  for (int j = 0; j < 4; j++) {
    const int col = bn + wn + j * 16 + l16;
    const float bv = bias[col];
#pragma unroll
    for (int i = 0; i < 4; i++) {
#pragma unroll
      for (int r = 0; r < 4; r++) {
        const int row = bm + wm + i * 16 + quad * 4 + r;
        const float v = acc[i][j][r] + bv;
        if (OUT_F32)
          ((float*)Cv)[(size_t)row * N + col] = v;
        else
          ((bf16_t*)Cv)[(size_t)row * N + col] = (bf16_t)v;
      }
    }
  }
}

#if HAVE_MFMA16
// ---------------------------------------------------------------------------
// R14 attention: S^T = K@Q^T (16x16x32), P stays in registers as the K=16
// MFMA A-fragment; O += P@V via mfma_f32_16x16x16_bf16. Double-buffered
// sK/sVt, ONE barrier per 64-key tile. Fixed-M softmax.
// sK : (t,d) at t*64 + (((d>>3) ^ (t&7))<<3) + (d&7)        [8 KB/buf]
// sVt: (d,t) at d*64 + (((t>>2) ^ (d&15))<<2) + (t&3)       [8 KB/buf]
// Main loop = full tiles only (branchless); diagonal tile hoisted after.
// Balance: X remapped so each CU's 4 resident blocks have sum(X)==62.
// ---------------------------------------------------------------------------
__global__ __launch_bounds__(256, 4) void attn_kernel(
    const bf16_t* __restrict__ qkv, bf16_t* __restrict__ Y) {
  constexpr int T = 2048, C3 = 3072;
  constexpr float CSC = 0.18033688f;  // 0.125 * log2(e)
  constexpr float MB = 20.0f;
  __shared__ __align__(16) bf16_t sK[2][64 * 64];
  __shared__ __align__(16) bf16_t sVt[2][64 * 64];

  const int tid = threadIdx.x;
  const int wave = tid >> 6, lane = tid & 63;
  const int quad = lane >> 4, l16 = lane & 15;
  const int bh = blockIdx.y;
  // causal-depth balance remap (bijective in bx for each bh):
  const int flip = (bh >> 3) & 1;
  const int vv = ((int)blockIdx.x + ((bh >> 4) & 1) * 8) & 31;
  const int X = flip ? (31 - vv) : vv;
  const int q0 = X * 64;
  const int b = bh >> 4, h = bh & 15;
  const size_t base = (size_t)b * T * C3 + (size_t)h * 64;

  // Q as B-operand: lane n=l16=query, k = quad*8+j
  const int qrow = q0 + wave * 16 + l16;
  const bf16x8 qf0 = *(const bf16x8*)&qkv[base + (size_t)qrow * C3 + quad * 8];
  const bf16x8 qf1 =
      *(const bf16x8*)&qkv[base + (size_t)qrow * C3 + 32 + quad * 8];

  f32x4 o[4] = {};   // O: lane holds rows (query) quad*4+r, col d = n16*16+l16
  f32x4 l4 = {0.f, 0.f, 0.f, 0.f};  // 4 parallel partial-sum chains

  // K staging: (t = tid>>2 key row, seg = tid&3)
  const int t = tid >> 2, seg = tid & 3;
  const bf16_t* gK = &qkv[base + (size_t)t * C3 + 1024 + seg * 16];
  // V staging: (kq = tid>>4 key-quad, dq = tid&15 d-quad)
  const int kq = tid >> 4, dq = tid & 15;
  const bf16_t* gV = &qkv[base + (size_t)(4 * kq) * C3 + 2048 + dq * 4];

  bf16x8 kr0 = *(const bf16x8*)gK;
  bf16x8 kr1 = *(const bf16x8*)(gK + 8);
  bf16x4 vA0 = *(const bf16x4*)gV;
  bf16x4 vA1 = *(const bf16x4*)(gV + C3);
  bf16x4 vA2 = *(const bf16x4*)(gV + 2 * C3);
  bf16x4 vA3 = *(const bf16x4*)(gV + 3 * C3);

  // ---- main loop: tiles 0..X-1, all keys < all queries: branch-free ----
  for (int kt = 0; kt < X; kt++) {
    const int p = kt & 1;
    // stage K (2 b128, swizzled) and V (4 b64, key-quad granules)
    *(bf16x8*)&sK[p][t * 64 + (((2 * seg + 0) ^ (t & 7)) << 3)] = kr0;
    *(bf16x8*)&sK[p][t * 64 + (((2 * seg + 1) ^ (t & 7)) << 3)] = kr1;
#pragma unroll
    for (int i = 0; i < 4; i++) {
      const int d = dq * 4 + i;
      bf16x4 w;
      w[0] = vA0[i]; w[1] = vA1[i]; w[2] = vA2[i]; w[3] = vA3[i];
      *(bf16x4*)&sVt[p][d * 64 + ((kq ^ (d & 15)) << 2)] = w;
    }
    // prefetch next tile (kt+1 <= X always valid); overlaps compute
    {
      const size_t off = (size_t)(kt + 1) * 64 * C3;
      kr0 = *(const bf16x8*)(gK + off);
      kr1 = *(const bf16x8*)(gK + off + 8);
      vA0 = *(const bf16x4*)(gV + off);
      vA1 = *(const bf16x4*)(gV + off + C3);
      vA2 = *(const bf16x4*)(gV + off + 2 * C3);
      vA3 = *(const bf16x4*)(gV + off + 3 * C3);
    }
    __syncthreads();  // single barrier: buf p visible; buf 1-p free

#pragma unroll
    for (int j = 0; j < 4; j++) {
      // S^T j-tile: A = K-frag (lane m=l16 -> key j*16+l16), B = Q-frag
      const int trow = j * 16 + l16;
      bf16x8 kf0 =
          *(const bf16x8*)&sK[p][trow * 64 + ((quad ^ (trow & 7)) << 3)];
      bf16x8 kf1 =
          *(const bf16x8*)&sK[p][trow * 64 + (((4 + quad) ^ (trow & 7)) << 3)];
      f32x4 s2 = {};
      __builtin_amdgcn_s_setprio(1);
      s2 = __builtin_amdgcn_mfma_f32_16x16x32_bf16(kf0, qf0, s2, 0, 0, 0);
      s2 = __builtin_amdgcn_mfma_f32_16x16x32_bf16(kf1, qf1, s2, 0, 0, 0);
      __builtin_amdgcn_s_setprio(0);
#pragma unroll
      for (int r = 0; r < 4; r++) s2[r] = EXP2F(fmaf(s2[r], CSC, -MB));
      l4 += s2;  // 4 parallel chains
      bf16x4 pb;
      pb[0] = (bf16_t)s2[0]; pb[1] = (bf16_t)s2[1];
      pb[2] = (bf16_t)s2[2]; pb[3] = (bf16_t)s2[3];
      union { bf16x4 bv; short4v sv; } u;
      u.bv = pb;
      const short4v pa = u.sv;
      __builtin_amdgcn_s_setprio(1);
#pragma unroll
      for (int n16 = 0; n16 < 4; n16++) {
        const int d = n16 * 16 + l16;
        const short4v vf = *(const short4v*)&sVt[p][d * 64 +
                                                    (((j * 4 + quad) ^ (d & 15))
                                                     << 2)];
        o[n16] =
            __builtin_amdgcn_mfma_f32_16x16x16bf16_1k(pa, vf, o[n16], 0, 0, 0);
      }
      __builtin_amdgcn_s_setprio(0);
    }
  }

  // ---- diagonal tile kt == X (hoisted; j-skip + diag mask) ----
  {
    const int p = X & 1;
    *(bf16x8*)&sK[p][t * 64 + (((2 * seg + 0) ^ (t & 7)) << 3)] = kr0;
    *(bf16x8*)&sK[p][t * 64 + (((2 * seg + 1) ^ (t & 7)) << 3)] = kr1;
#pragma unroll
    for (int i = 0; i < 4; i++) {
      const int d = dq * 4 + i;
      bf16x4 w;
      w[0] = vA0[i]; w[1] = vA1[i]; w[2] = vA2[i]; w[3] = vA3[i];
      *(bf16x4*)&sVt[p][d * 64 + ((kq ^ (d & 15)) << 2)] = w;
    }
    __syncthreads();

#pragma unroll
    for (int j = 0; j < 4; j++) {
      if (j > wave) continue;  // wave-uniform; P would be all-zero
      const int trow = j * 16 + l16;
      bf16x8 kf0 =
          *(const bf16x8*)&sK[p][trow * 64 + ((quad ^ (trow & 7)) << 3)];
      bf16x8 kf1 =
          *(const bf16x8*)&sK[p][trow * 64 + (((4 + quad) ^ (trow & 7)) << 3)];
      f32x4 s2 = {};
      __builtin_amdgcn_s_setprio(1);
      s2 = __builtin_amdgcn_mfma_f32_16x16x32_bf16(kf0, qf0, s2, 0, 0, 0);
      s2 = __builtin_amdgcn_mfma_f32_16x16x32_bf16(kf1, qf1, s2, 0, 0, 0);
      __builtin_amdgcn_s_setprio(0);
      const bool diag = (j == wave);
#pragma unroll
      for (int r = 0; r < 4; r++) {
        float pv = EXP2F(fmaf(s2[r], CSC, -MB));
        if (diag && (quad * 4 + r > l16)) pv = 0.f;
        s2[r] = pv;
      }
      l4 += s2;
      bf16x4 pb;
      pb[0] = (bf16_t)s2[0]; pb[1] = (bf16_t)s2[1];
      pb[2] = (bf16_t)s2[2]; pb[3] = (bf16_t)s2[3];
      union { bf16x4 bv; short4v sv; } u;
      u.bv = pb;
      const short4v pa = u.sv;
      __builtin_amdgcn_s_setprio(1);
#pragma unroll
      for (int n16 = 0; n16 < 4; n16++) {
        const int d = n16 * 16 + l16;
        const short4v vf = *(const short4v*)&sVt[p][d * 64 +
                                                    (((j * 4 + quad) ^ (d & 15))
                                                     << 2)];
        o[n16] =
            __builtin_amdgcn_mfma_f32_16x16x16bf16_1k(pa, vf, o[n16], 0, 0, 0);
      }
      __builtin_amdgcn_s_setprio(0);
    }
  }

  // epilogue: complete l across quads (2 shuffles), redistribute, store
  float l_acc = (l4[0] + l4[1]) + (l4[2] + l4[3]);
  l_acc += __shfl_xor(l_acc, 16);
  l_acc += __shfl_xor(l_acc, 32);
#pragma unroll
  for (int r = 0; r < 4; r++) {
    const float lr = __shfl(l_acc, quad * 4 + r);
    const float inv = 1.0f / lr;
    const int row = q0 + wave * 16 + quad * 4 + r;
#pragma unroll
    for (int n16 = 0; n16 < 4; n16++)
      Y[((size_t)b * T + row) * 1024 + h * 64 + n16 * 16 + l16] =
          (bf16_t)(o[n16][r] * inv);
  }
}
#else
// ---------------------------------------------------------------------------
// Fallback = R10 attention (sP round-trip), with the R12 balance remap.
// ---------------------------------------------------------------------------
__global__ __launch_bounds__(256, 4) void attn_kernel(
    const bf16_t* __restrict__ qkv, bf16_t* __restrict__ Y) {
  constexpr int T = 2048, C3 = 3072;
  constexpr float CSC = 0.18033688f;
  constexpr float MB = 20.0f;
  __shared__ __align__(16) bf16_t sK[64 * 64];
  __shared__ __align__(16) bf16_t sVt[64 * 64];
  __shared__ __align__(16) bf16_t sP[4][16 * 64];

  const int tid = threadIdx.x;
  const int wave = tid >> 6, lane = tid & 63;
  const int quad = lane >> 4, l16 = lane & 15;
  const int bh = blockIdx.y;
  const int flip = (bh >> 3) & 1;
  const int vv = ((int)blockIdx.x + ((bh >> 4) & 1) * 8) & 31;
  const int X = flip ? (31 - vv) : vv;
  const int q0 = X * 64;
  const int b = bh >> 4, h = bh & 15;
  const size_t base = (size_t)b * T * C3 + (size_t)h * 64;

  const int qrow = q0 + wave * 16 + l16;
  const bf16x8 qf0 = *(const bf16x8*)&qkv[base + (size_t)qrow * C3 + quad * 8];
  const bf16x8 qf1 =
      *(const bf16x8*)&qkv[base + (size_t)qrow * C3 + 32 + quad * 8];

  f32x4 o[4] = {};
  float l_i[4] = {0.f, 0.f, 0.f, 0.f};

  const int t = tid >> 2, seg = tid & 3;
  const int tk = t & 7, tg3 = t >> 3;
  const bf16_t* gK = &qkv[base + (size_t)t * C3 + 1024 + seg * 16];
  const bf16_t* gV = &qkv[base + (size_t)t * C3 + 2048 + seg * 16];

  const int ktiles = X + 1;

  bf16x8 kr0 = *(const bf16x8*)gK;
  bf16x8 kr1 = *(const bf16x8*)(gK + 8);
  bf16x8 vr0 = *(const bf16x8*)gV;
  bf16x8 vr1 = *(const bf16x8*)(gV + 8);

  for (int kt = 0; kt < ktiles; kt++) {
    __syncthreads();
    *(bf16x8*)&sK[t * 64 + (((2 * seg + 0) ^ tk) << 3)] = kr0;
    *(bf16x8*)&sK[t * 64 + (((2 * seg + 1) ^ tk) << 3)] = kr1;
#pragma unroll
    for (int i = 0; i < 8; i++) {
      const int d = seg * 16 + i;
      sVt[d * 64 + ((tg3 ^ (d >> 3)) << 3) + (t & 7)] = vr0[i];
    }
#pragma unroll
    for (int i = 0; i < 8; i++) {
      const int d = seg * 16 + 8 + i;
      sVt[d * 64 + ((tg3 ^ (d >> 3)) << 3) + (t & 7)] = vr1[i];
    }
    __syncthreads();

    if (kt + 1 < ktiles) {
      const size_t off = (size_t)(kt + 1) * 64 * C3;
      kr0 = *(const bf16x8*)(gK + off);
      kr1 = *(const bf16x8*)(gK + off + 8);
      vr0 = *(const bf16x8*)(gV + off);
      vr1 = *(const bf16x8*)(gV + off + 8);
    }

    f32x4 s[4] = {};
#pragma unroll
    for (int j = 0; j < 4; j++) {
      const int kkey = l16 & 7;
      bf16x8 kf0 =
          *(const bf16x8*)&sK[(j * 16 + l16) * 64 + ((quad ^ kkey) << 3)];
      bf16x8 kf1 =
          *(const bf16x8*)&sK[(j * 16 + l16) * 64 + (((4 + quad) ^ kkey) << 3)];
      s[j] = __builtin_amdgcn_mfma_f32_16x16x32_bf16(qf0, kf0, s[j], 0, 0, 0);
      s[j] = __builtin_amdgcn_mfma_f32_16x16x32_bf16(qf1, kf1, s[j], 0, 0, 0);
    }

#pragma unroll
    for (int j = 0; j < 4; j++)
#pragma unroll
      for (int r = 0; r < 4; r++) s[j][r] = EXP2F(fmaf(s[j][r], CSC, -MB));
    if (kt == ktiles - 1) {
      const int k0 = kt * 64;
#pragma unroll
      for (int j = 0; j < 4; j++) {
        const int kcol = k0 + j * 16 + l16;
#pragma unroll
        for (int r = 0; r < 4; r++)
          if (kcol > q0 + wave * 16 + quad * 4 + r) s[j][r] = 0.f;
      }
    }
#pragma unroll
    for (int j = 0; j < 4; j++)
#pragma unroll
      for (int r = 0; r < 4; r++) l_i[r] += s[j][r];

    bf16_t* sp = &sP[wave][0];
#pragma unroll
    for (int j = 0; j < 4; j++)
#pragma unroll
      for (int r = 0; r < 4; r++) {
        const int m = quad * 4 + r;
        const int kw = (m + (m >> 3)) & 7;
        sp[m * 64 + ((((2 * j + (l16 >> 3)) ^ kw)) << 3) + (l16 & 7)] =
            (bf16_t)s[j][r];
      }

    const int kap = (l16 + (l16 >> 3)) & 7;
#pragma unroll
    for (int s2 = 0; s2 < 2; s2++) {
      bf16x8 pf =
          *(const bf16x8*)&sp[l16 * 64 + (((4 * s2 + quad) ^ kap) << 3)];
#pragma unroll
      for (int j = 0; j < 4; j++) {
        const int d = j * 16 + l16;
        bf16x8 vf =
            *(const bf16x8*)&sVt[d * 64 + (((4 * s2 + quad) ^ (d >> 3)) << 3)];
        o[j] = __builtin_amdgcn_mfma_f32_16x16x32_bf16(pf, vf, o[j], 0, 0, 0);
      }
    }
  }

#pragma unroll
  for (int r = 0; r < 4; r++) {
    float l = l_i[r];
#pragma unroll
    for (int off = 1; off < 16; off <<= 1) l += __shfl_xor(l, off);
    const float inv = 1.0f / l;
    const int row = q0 + wave * 16 + quad * 4 + r;
#pragma unroll
    for (int j = 0; j < 4; j++)
      Y[((size_t)b * T + row) * 1024 + h * 64 + j * 16 + l16] =
          (bf16_t)(o[j][r] * inv);
  }
}
#endif

// ---------------------------------------------------------------------------
extern "C" void kernel_launch(void* const* d_in, const int* in_sizes, int n_in,
                              void* d_out, int out_size, void* d_ws,
                              size_t ws_size, hipStream_t stream) {
  const float* x = nullptr;
  const float* w_qkv = nullptr;
  const float* b_qkv = nullptr;
  const float* w_out = nullptr;
  const float* b_out = nullptr;
  for (int i = 0; i < n_in; i++) {
    switch (in_sizes[i]) {
      case 4194304: x = (const float*)d_in[i]; break;
      case 3145728: w_qkv = (const float*)d_in[i]; break;
      case 3072:    b_qkv = (const float*)d_in[i]; break;
      case 1048576: w_out = (const float*)d_in[i]; break;
      case 1024:    b_out = (const float*)d_in[i]; break;
      default: break;
    }
  }
  float* out = (float*)d_out;  // FP32 output

  bf16_t* xb = (bf16_t*)d_ws;
  bf16_t* wqkvT = xb + (size_t)4194304;
  bf16_t* woutT = wqkvT + (size_t)3145728;
  bf16_t* qkv = woutT + (size_t)1048576;
  bf16_t* Y = qkv + (size_t)12582912;

  prep_kernel<<<6144, 256, 0, stream>>>(x, w_qkv, w_out, xb, wqkvT, woutT);
  gemm_bt_kernel<false><<<dim3(24, 32), 256, 0, stream>>>(
      xb, wqkvT, b_qkv, (void*)qkv, 4096, 3072, 1024);
  attn_kernel<<<dim3(32, 32), 256, 0, stream>>>(qkv, Y);
  gemm_bt_kernel<true><<<dim3(8, 32), 256, 0, stream>>>(
      Y, woutT, b_out, (void*)out, 4096, 1024, 1024);
}

// Round 6
// 185.710 us; speedup vs baseline: 1.0528x; 1.0285x over previous
//
#include <hip/hip_runtime.h>
#include <hip/hip_bf16.h>
#include <stdint.h>

// SelfAttention B=2,T=2048,C=1024,H=16,hd=64. Inputs fp32, output fp32.
// R17: split-K attn REVERTED (R15/R16 failed with bit-identical error
// across different partial storage/precision => deterministic logic bug;
// per pre-committed falsifier, back to proven R14 attn: 47.7us, passing).
// New this round: gemm2 was grid (8,32)=256 blocks = 1 block/CU -> the
// staging barrier-drain has no cross-block overlap (m97 structure needs
// ~3 blk/CU). gemm_bt64_kernel: BM=64,BN=128 same proven pattern, grid
// (8,64)=512 blocks = 2/CU. Attn keeps: R12 balance remap, hoisted diag,
// f32x4 l-acc, builtin exp2, setprio.

typedef __bf16 bf16_t;
typedef __attribute__((ext_vector_type(8))) __bf16 bf16x8;
typedef __attribute__((ext_vector_type(4))) __bf16 bf16x4;
typedef __attribute__((ext_vector_type(4))) short short4v;
typedef __attribute__((ext_vector_type(4))) float f32x4;

static_assert(sizeof(bf16x8) == 16, "bf16x8 must be 16B");

#if defined(__has_builtin)
#if __has_builtin(__builtin_amdgcn_mfma_f32_16x16x16bf16_1k)
#define HAVE_MFMA16 1
#endif
#if __has_builtin(__builtin_amdgcn_exp2f)
#define EXP2F(x) __builtin_amdgcn_exp2f(x)
#endif
#endif
#ifndef HAVE_MFMA16
#define HAVE_MFMA16 0
#endif
#ifndef EXP2F
#define EXP2F(x) exp2f(x)
#endif

// async global->LDS, 16B/lane. LDS dest = wave-uniform base + lane*16.
__device__ inline void async_copy16(const bf16_t* gsrc, bf16_t* lds_dst) {
  __builtin_amdgcn_global_load_lds(
      (const __attribute__((address_space(1))) uint32_t*)(const void*)gsrc,
      (__attribute__((address_space(3))) uint32_t*)(void*)lds_dst,
      16, 0, 0);
}

// ---------------------------------------------------------------------------
// Merged prep: blocks [0,2048) convx; [2048,5120) transpose w_qkv;
// [5120,6144) transpose w_out.
// ---------------------------------------------------------------------------
__global__ __launch_bounds__(256) void prep_kernel(
    const float* __restrict__ x, const float* __restrict__ wq,
    const float* __restrict__ wo, bf16_t* __restrict__ xb,
    bf16_t* __restrict__ wqkvT, bf16_t* __restrict__ woutT) {
  __shared__ bf16_t tile[32][33];
  const int bid = blockIdx.x;
  if (bid < 2048) {
    const int i = bid * 256 + threadIdx.x;  // < 524288
    const float4* s = (const float4*)x;
    float4 a = s[i * 2], b = s[i * 2 + 1];
    bf16x8 o;
    o[0] = (bf16_t)a.x; o[1] = (bf16_t)a.y; o[2] = (bf16_t)a.z; o[3] = (bf16_t)a.w;
    o[4] = (bf16_t)b.x; o[5] = (bf16_t)b.y; o[6] = (bf16_t)b.z; o[7] = (bf16_t)b.w;
    ((bf16x8*)xb)[i] = o;
    return;
  }
  const bool isq = bid < 5120;
  const int id = isq ? bid - 2048 : bid - 5120;
  const int C = isq ? 3072 : 1024;
  const int R = 1024;
  const int nbx = isq ? 96 : 32;
  const float* in = isq ? wq : wo;
  bf16_t* out = isq ? wqkvT : woutT;
  const int c0 = (id % nbx) * 32, r0 = (id / nbx) * 32;
  const int tx = threadIdx.x & 31;
  const int ty = threadIdx.x >> 5;
#pragma unroll
  for (int i = 0; i < 4; i++) {
    int r = ty + i * 8;
    tile[r][tx] = (bf16_t)in[(size_t)(r0 + r) * C + c0 + tx];
  }
  __syncthreads();
#pragma unroll
  for (int i = 0; i < 4; i++) {
    int r = ty + i * 8;
    out[(size_t)(c0 + r) * R + r0 + tx] = tile[tx][r];
  }
}

// ---------------------------------------------------------------------------
// C[M,N] = A[M,K] @ Bt[N,K]^T + bias[N]. bf16 in; OUT_F32 selects store type.
// BM=BN=128, BK=32, 4 waves 2x2. m97-style global_load_lds staging. (R10)
// ---------------------------------------------------------------------------
template <bool OUT_F32>
__global__ __launch_bounds__(256) void gemm_bt_kernel(
    const bf16_t* __restrict__ A, const bf16_t* __restrict__ Bt,
    const float* __restrict__ bias, void* __restrict__ Cv, int M, int N,
    int K) {
  __shared__ __align__(16) bf16_t sA[128 * 32];
  __shared__ __align__(16) bf16_t sB[128 * 32];
  const int tid = threadIdx.x;
  const int wave = tid >> 6, lane = tid & 63;
  const int quad = lane >> 4, l16 = lane & 15;
  const int wm = (wave >> 1) * 64, wn = (wave & 1) * 64;
  const int bm = blockIdx.y * 128, bn = blockIdx.x * 128;

  const int srow = wave * 16 + (lane >> 2);
  const int skk = (lane & 3) * 8;
  const bf16_t* gA = A + (size_t)(bm + srow) * K + skk;
  const bf16_t* gB = Bt + (size_t)(bn + srow) * K + skk;
  bf16_t* lA = sA + wave * 512;
  bf16_t* lB = sB + wave * 512;

  f32x4 acc[4][4] = {};

  for (int k0 = 0; k0 < K; k0 += 32) {
    __syncthreads();
    async_copy16(gA + k0, lA);
    async_copy16(gA + (size_t)64 * K + k0, lA + 2048);
    async_copy16(gB + k0, lB);
    async_copy16(gB + (size_t)64 * K + k0, lB + 2048);
    __syncthreads();

    bf16x8 af[4], bfr[4];
#pragma unroll
    for (int i = 0; i < 4; i++)
      af[i] = *(const bf16x8*)&sA[(wm + i * 16 + l16) * 32 + quad * 8];
#pragma unroll
    for (int j = 0; j < 4; j++)
      bfr[j] = *(const bf16x8*)&sB[(wn + j * 16 + l16) * 32 + quad * 8];
#pragma unroll
    for (int i = 0; i < 4; i++)
#pragma unroll
      for (int j = 0; j < 4; j++)
        acc[i][j] = __builtin_amdgcn_mfma_f32_16x16x32_bf16(af[i], bfr[j],
                                                            acc[i][j], 0, 0, 0);
  }

#pragma unroll
  for (int j = 0; j < 4; j++) {
    const int col = bn + wn + j * 16 + l16;
    const float bv = bias[col];
#pragma unroll
    for (int i = 0; i < 4; i++) {
#pragma unroll
      for (int r = 0; r < 4; r++) {
        const int row = bm + wm + i * 16 + quad * 4 + r;
        const float v = acc[i][j][r] + bv;
        if (OUT_F32)
          ((float*)Cv)[(size_t)row * N + col] = v;
        else
          ((bf16_t*)Cv)[(size_t)row * N + col] = (bf16_t)v;
      }
    }
  }
}

// ---------------------------------------------------------------------------
// BM=64, BN=128 variant (f32 out) for gemm2: grid (N/128, M/64) = 512 blocks
// = 2 blocks/CU (vs 1 for the 128x128 tile at M=4096,N=1024). Same staging
// scheme: wave covers 16 rows x 32 cols per async_copy16 call.
// ---------------------------------------------------------------------------
__global__ __launch_bounds__(256) void gemm_bt64_kernel(
    const bf16_t* __restrict__ A, const bf16_t* __restrict__ Bt,
    const float* __restrict__ bias, float* __restrict__ C, int M, int N,
    int K) {
  __shared__ __align__(16) bf16_t sA[64 * 32];   // 4 KB
  __shared__ __align__(16) bf16_t sB[128 * 32];  // 8 KB
  const int tid = threadIdx.x;
  const int wave = tid >> 6, lane = tid & 63;
  const int quad = lane >> 4, l16 = lane & 15;
  const int wm = (wave >> 1) * 32, wn = (wave & 1) * 64;
  const int bm = blockIdx.y * 64, bn = blockIdx.x * 128;

  const int srow = wave * 16 + (lane >> 2);
  const int skk = (lane & 3) * 8;
  const bf16_t* gA = A + (size_t)(bm + srow) * K + skk;
  const bf16_t* gB = Bt + (size_t)(bn + srow) * K + skk;
  bf16_t* lA = sA + wave * 512;
  bf16_t* lB = sB + wave * 512;

  f32x4 acc[2][4] = {};

  for (int k0 = 0; k0 < K; k0 += 32) {
    __syncthreads();
    async_copy16(gA + k0, lA);                          // A rows [0,64)
    async_copy16(gB + k0, lB);                          // B rows [0,64)
    async_copy16(gB + (size_t)64 * K + k0, lB + 2048);  // B rows [64,128)
    __syncthreads();

    bf16x8 af[2], bfr[4];
#pragma unroll
    for (int i = 0; i < 2; i++)
      af[i] = *(const bf16x8*)&sA[(wm + i * 16 + l16) * 32 + quad * 8];
#pragma unroll
    for (int j = 0; j < 4; j++)
      bfr[j] = *(const bf16x8*)&sB[(wn + j * 16 + l16) * 32 + quad * 8];
#pragma unroll
    for (int i = 0; i < 2; i++)
#pragma unroll
      for (int j = 0; j < 4; j++)
        acc[i][j] = __builtin_amdgcn_mfma_f32_16x16x32_bf16(af[i], bfr[j],
                                                            acc[i][j], 0, 0, 0);
  }

#pragma unroll
  for (int j = 0; j < 4; j++) {
    const int col = bn + wn + j * 16 + l16;
    const float bv = bias[col];
#pragma unroll
    for (int i = 0; i < 2; i++) {
#pragma unroll
      for (int r = 0; r < 4; r++) {
        const int row = bm + wm + i * 16 + quad * 4 + r;
        C[(size_t)row * N + col] = acc[i][j][r] + bv;
      }
    }
  }
}

#if HAVE_MFMA16
// ---------------------------------------------------------------------------
// R14 attention (proven): S^T = K@Q^T (16x16x32), P stays in registers as
// the K=16 MFMA A-fragment; O += P@V via mfma_f32_16x16x16_bf16. Double-
// buffered sK/sVt, ONE barrier per 64-key tile. Fixed-M softmax.
// sK : (t,d) at t*64 + (((d>>3) ^ (t&7))<<3) + (d&7)        [8 KB/buf]
// sVt: (d,t) at d*64 + (((t>>2) ^ (d&15))<<2) + (t&3)       [8 KB/buf]
// Main loop = full tiles only (branchless); diagonal tile hoisted after.
// Balance: X remapped so each CU's 4 resident blocks have sum(X)==62.
// ---------------------------------------------------------------------------
__global__ __launch_bounds__(256, 4) void attn_kernel(
    const bf16_t* __restrict__ qkv, bf16_t* __restrict__ Y) {
  constexpr int T = 2048, C3 = 3072;
  constexpr float CSC = 0.18033688f;  // 0.125 * log2(e)
  constexpr float MB = 20.0f;
  __shared__ __align__(16) bf16_t sK[2][64 * 64];
  __shared__ __align__(16) bf16_t sVt[2][64 * 64];

  const int tid = threadIdx.x;
  const int wave = tid >> 6, lane = tid & 63;
  const int quad = lane >> 4, l16 = lane & 15;
  const int bh = blockIdx.y;
  // causal-depth balance remap (bijective in bx for each bh):
  const int flip = (bh >> 3) & 1;
  const int vv = ((int)blockIdx.x + ((bh >> 4) & 1) * 8) & 31;
  const int X = flip ? (31 - vv) : vv;
  const int q0 = X * 64;
  const int b = bh >> 4, h = bh & 15;
  const size_t base = (size_t)b * T * C3 + (size_t)h * 64;

  // Q as B-operand: lane n=l16=query, k = quad*8+j
  const int qrow = q0 + wave * 16 + l16;
  const bf16x8 qf0 = *(const bf16x8*)&qkv[base + (size_t)qrow * C3 + quad * 8];
  const bf16x8 qf1 =
      *(const bf16x8*)&qkv[base + (size_t)qrow * C3 + 32 + quad * 8];

  f32x4 o[4] = {};   // O: lane holds rows (query) quad*4+r, col d = n16*16+l16
  f32x4 l4 = {0.f, 0.f, 0.f, 0.f};  // 4 parallel partial-sum chains

  // K staging: (t = tid>>2 key row, seg = tid&3)
  const int t = tid >> 2, seg = tid & 3;
  const bf16_t* gK = &qkv[base + (size_t)t * C3 + 1024 + seg * 16];
  // V staging: (kq = tid>>4 key-quad, dq = tid&15 d-quad)
  const int kq = tid >> 4, dq = tid & 15;
  const bf16_t* gV = &qkv[base + (size_t)(4 * kq) * C3 + 2048 + dq * 4];

  bf16x8 kr0 = *(const bf16x8*)gK;
  bf16x8 kr1 = *(const bf16x8*)(gK + 8);
  bf16x4 vA0 = *(const bf16x4*)gV;
  bf16x4 vA1 = *(const bf16x4*)(gV + C3);
  bf16x4 vA2 = *(const bf16x4*)(gV + 2 * C3);
  bf16x4 vA3 = *(const bf16x4*)(gV + 3 * C3);

  // ---- main loop: tiles 0..X-1, all keys < all queries: branch-free ----
  for (int kt = 0; kt < X; kt++) {
    const int p = kt & 1;
    // stage K (2 b128, swizzled) and V (4 b64, key-quad granules)
    *(bf16x8*)&sK[p][t * 64 + (((2 * seg + 0) ^ (t & 7)) << 3)] = kr0;
    *(bf16x8*)&sK[p][t * 64 + (((2 * seg + 1) ^ (t & 7)) << 3)] = kr1;
#pragma unroll
    for (int i = 0; i < 4; i++) {
      const int d = dq * 4 + i;
      bf16x4 w;
      w[0] = vA0[i]; w[1] = vA1[i]; w[2] = vA2[i]; w[3] = vA3[i];
      *(bf16x4*)&sVt[p][d * 64 + ((kq ^ (d & 15)) << 2)] = w;
    }
    // prefetch next tile (kt+1 <= X always valid); overlaps compute
    {
      const size_t off = (size_t)(kt + 1) * 64 * C3;
      kr0 = *(const bf16x8*)(gK + off);
      kr1 = *(const bf16x8*)(gK + off + 8);
      vA0 = *(const bf16x4*)(gV + off);
      vA1 = *(const bf16x4*)(gV + off + C3);
      vA2 = *(const bf16x4*)(gV + off + 2 * C3);
      vA3 = *(const bf16x4*)(gV + off + 3 * C3);
    }
    __syncthreads();  // single barrier: buf p visible; buf 1-p free

#pragma unroll
    for (int j = 0; j < 4; j++) {
      // S^T j-tile: A = K-frag (lane m=l16 -> key j*16+l16), B = Q-frag
      const int trow = j * 16 + l16;
      bf16x8 kf0 =
          *(const bf16x8*)&sK[p][trow * 64 + ((quad ^ (trow & 7)) << 3)];
      bf16x8 kf1 =
          *(const bf16x8*)&sK[p][trow * 64 + (((4 + quad) ^ (trow & 7)) << 3)];
      f32x4 s2 = {};
      __builtin_amdgcn_s_setprio(1);
      s2 = __builtin_amdgcn_mfma_f32_16x16x32_bf16(kf0, qf0, s2, 0, 0, 0);
      s2 = __builtin_amdgcn_mfma_f32_16x16x32_bf16(kf1, qf1, s2, 0, 0, 0);
      __builtin_amdgcn_s_setprio(0);
#pragma unroll
      for (int r = 0; r < 4; r++) s2[r] = EXP2F(fmaf(s2[r], CSC, -MB));
      l4 += s2;  // 4 parallel chains
      bf16x4 pb;
      pb[0] = (bf16_t)s2[0]; pb[1] = (bf16_t)s2[1];
      pb[2] = (bf16_t)s2[2]; pb[3] = (bf16_t)s2[3];
      union { bf16x4 bv; short4v sv; } u;
      u.bv = pb;
      const short4v pa = u.sv;
      __builtin_amdgcn_s_setprio(1);
#pragma unroll
      for (int n16 = 0; n16 < 4; n16++) {
        const int d = n16 * 16 + l16;
        const short4v vf = *(const short4v*)&sVt[p][d * 64 +
                                                    (((j * 4 + quad) ^ (d & 15))
                                                     << 2)];
        o[n16] =
            __builtin_amdgcn_mfma_f32_16x16x16bf16_1k(pa, vf, o[n16], 0, 0, 0);
      }
      __builtin_amdgcn_s_setprio(0);
    }
  }

  // ---- diagonal tile kt == X (hoisted; j-skip + diag mask) ----
  {
    const int p = X & 1;
    *(bf16x8*)&sK[p][t * 64 + (((2 * seg + 0) ^ (t & 7)) << 3)] = kr0;
    *(bf16x8*)&sK[p][t * 64 + (((2 * seg + 1) ^ (t & 7)) << 3)] = kr1;
#pragma unroll
    for (int i = 0; i < 4; i++) {
      const int d = dq * 4 + i;
      bf16x4 w;
      w[0] = vA0[i]; w[1] = vA1[i]; w[2] = vA2[i]; w[3] = vA3[i];
      *(bf16x4*)&sVt[p][d * 64 + ((kq ^ (d & 15)) << 2)] = w;
    }
    __syncthreads();

#pragma unroll
    for (int j = 0; j < 4; j++) {
      if (j > wave) continue;  // wave-uniform; P would be all-zero
      const int trow = j * 16 + l16;
      bf16x8 kf0 =
          *(const bf16x8*)&sK[p][trow * 64 + ((quad ^ (trow & 7)) << 3)];
      bf16x8 kf1 =
          *(const bf16x8*)&sK[p][trow * 64 + (((4 + quad) ^ (trow & 7)) << 3)];
      f32x4 s2 = {};
      __builtin_amdgcn_s_setprio(1);
      s2 = __builtin_amdgcn_mfma_f32_16x16x32_bf16(kf0, qf0, s2, 0, 0, 0);
      s2 = __builtin_amdgcn_mfma_f32_16x16x32_bf16(kf1, qf1, s2, 0, 0, 0);
      __builtin_amdgcn_s_setprio(0);
      const bool diag = (j == wave);
#pragma unroll
      for (int r = 0; r < 4; r++) {
        float pv = EXP2F(fmaf(s2[r], CSC, -MB));
        if (diag && (quad * 4 + r > l16)) pv = 0.f;
        s2[r] = pv;
      }
      l4 += s2;
      bf16x4 pb;
      pb[0] = (bf16_t)s2[0]; pb[1] = (bf16_t)s2[1];
      pb[2] = (bf16_t)s2[2]; pb[3] = (bf16_t)s2[3];
      union { bf16x4 bv; short4v sv; } u;
      u.bv = pb;
      const short4v pa = u.sv;
      __builtin_amdgcn_s_setprio(1);
#pragma unroll
      for (int n16 = 0; n16 < 4; n16++) {
        const int d = n16 * 16 + l16;
        const short4v vf = *(const short4v*)&sVt[p][d * 64 +
                                                    (((j * 4 + quad) ^ (d & 15))
                                                     << 2)];
        o[n16] =
            __builtin_amdgcn_mfma_f32_16x16x16bf16_1k(pa, vf, o[n16], 0, 0, 0);
      }
      __builtin_amdgcn_s_setprio(0);
    }
  }

  // epilogue: complete l across quads (2 shuffles), redistribute, store
  float l_acc = (l4[0] + l4[1]) + (l4[2] + l4[3]);
  l_acc += __shfl_xor(l_acc, 16);
  l_acc += __shfl_xor(l_acc, 32);
#pragma unroll
  for (int r = 0; r < 4; r++) {
    const float lr = __shfl(l_acc, quad * 4 + r);
    const float inv = 1.0f / lr;
    const int row = q0 + wave * 16 + quad * 4 + r;
#pragma unroll
    for (int n16 = 0; n16 < 4; n16++)
      Y[((size_t)b * T + row) * 1024 + h * 64 + n16 * 16 + l16] =
          (bf16_t)(o[n16][r] * inv);
  }
}
#else
// ---------------------------------------------------------------------------
// Fallback = R10 attention (sP round-trip), with the R12 balance remap.
// ---------------------------------------------------------------------------
__global__ __launch_bounds__(256, 4) void attn_kernel(
    const bf16_t* __restrict__ qkv, bf16_t* __restrict__ Y) {
  constexpr int T = 2048, C3 = 3072;
  constexpr float CSC = 0.18033688f;
  constexpr float MB = 20.0f;
  __shared__ __align__(16) bf16_t sK[64 * 64];
  __shared__ __align__(16) bf16_t sVt[64 * 64];
  __shared__ __align__(16) bf16_t sP[4][16 * 64];

  const int tid = threadIdx.x;
  const int wave = tid >> 6, lane = tid & 63;
  const int quad = lane >> 4, l16 = lane & 15;
  const int bh = blockIdx.y;
  const int flip = (bh >> 3) & 1;
  const int vv = ((int)blockIdx.x + ((bh >> 4) & 1) * 8) & 31;
  const int X = flip ? (31 - vv) : vv;
  const int q0 = X * 64;
  const int b = bh >> 4, h = bh & 15;
  const size_t base = (size_t)b * T * C3 + (size_t)h * 64;

  const int qrow = q0 + wave * 16 + l16;
  const bf16x8 qf0 = *(const bf16x8*)&qkv[base + (size_t)qrow * C3 + quad * 8];
  const bf16x8 qf1 =
      *(const bf16x8*)&qkv[base + (size_t)qrow * C3 + 32 + quad * 8];

  f32x4 o[4] = {};
  float l_i[4] = {0.f, 0.f, 0.f, 0.f};

  const int t = tid >> 2, seg = tid & 3;
  const int tk = t & 7, tg3 = t >> 3;
  const bf16_t* gK = &qkv[base + (size_t)t * C3 + 1024 + seg * 16];
  const bf16_t* gV = &qkv[base + (size_t)t * C3 + 2048 + seg * 16];

  const int ktiles = X + 1;

  bf16x8 kr0 = *(const bf16x8*)gK;
  bf16x8 kr1 = *(const bf16x8*)(gK + 8);
  bf16x8 vr0 = *(const bf16x8*)gV;
  bf16x8 vr1 = *(const bf16x8*)(gV + 8);

  for (int kt = 0; kt < ktiles; kt++) {
    __syncthreads();
    *(bf16x8*)&sK[t * 64 + (((2 * seg + 0) ^ tk) << 3)] = kr0;
    *(bf16x8*)&sK[t * 64 + (((2 * seg + 1) ^ tk) << 3)] = kr1;
#pragma unroll
    for (int i = 0; i < 8; i++) {
      const int d = seg * 16 + i;
      sVt[d * 64 + ((tg3 ^ (d >> 3)) << 3) + (t & 7)] = vr0[i];
    }
#pragma unroll
    for (int i = 0; i < 8; i++) {
      const int d = seg * 16 + 8 + i;
      sVt[d * 64 + ((tg3 ^ (d >> 3)) << 3) + (t & 7)] = vr1[i];
    }
    __syncthreads();

    if (kt + 1 < ktiles) {
      const size_t off = (size_t)(kt + 1) * 64 * C3;
      kr0 = *(const bf16x8*)(gK + off);
      kr1 = *(const bf16x8*)(gK + off + 8);
      vr0 = *(const bf16x8*)(gV + off);
      vr1 = *(const bf16x8*)(gV + off + 8);
    }

    f32x4 s[4] = {};
#pragma unroll
    for (int j = 0; j < 4; j++) {
      const int kkey = l16 & 7;
      bf16x8 kf0 =
          *(const bf16x8*)&sK[(j * 16 + l16) * 64 + ((quad ^ kkey) << 3)];
      bf16x8 kf1 =
          *(const bf16x8*)&sK[(j * 16 + l16) * 64 + (((4 + quad) ^ kkey) << 3)];
      s[j] = __builtin_amdgcn_mfma_f32_16x16x32_bf16(qf0, kf0, s[j], 0, 0, 0);
      s[j] = __builtin_amdgcn_mfma_f32_16x16x32_bf16(qf1, kf1, s[j], 0, 0, 0);
    }

#pragma unroll
    for (int j = 0; j < 4; j++)
#pragma unroll
      for (int r = 0; r < 4; r++) s[j][r] = EXP2F(fmaf(s[j][r], CSC, -MB));
    if (kt == ktiles - 1) {
      const int k0 = kt * 64;
#pragma unroll
      for (int j = 0; j < 4; j++) {
        const int kcol = k0 + j * 16 + l16;
#pragma unroll
        for (int r = 0; r < 4; r++)
          if (kcol > q0 + wave * 16 + quad * 4 + r) s[j][r] = 0.f;
      }
    }
#pragma unroll
    for (int j = 0; j < 4; j++)
#pragma unroll
      for (int r = 0; r < 4; r++) l_i[r] += s[j][r];

    bf16_t* sp = &sP[wave][0];
#pragma unroll
    for (int j = 0; j < 4; j++)
#pragma unroll
      for (int r = 0; r < 4; r++) {
        const int m = quad * 4 + r;
        const int kw = (m + (m >> 3)) & 7;
        sp[m * 64 + ((((2 * j + (l16 >> 3)) ^ kw)) << 3) + (l16 & 7)] =
            (bf16_t)s[j][r];
      }

    const int kap = (l16 + (l16 >> 3)) & 7;
#pragma unroll
    for (int s2 = 0; s2 < 2; s2++) {
      bf16x8 pf =
          *(const bf16x8*)&sp[l16 * 64 + (((4 * s2 + quad) ^ kap) << 3)];
#pragma unroll
      for (int j = 0; j < 4; j++) {
        const int d = j * 16 + l16;
        bf16x8 vf =
            *(const bf16x8*)&sVt[d * 64 + (((4 * s2 + quad) ^ (d >> 3)) << 3)];
        o[j] = __builtin_amdgcn_mfma_f32_16x16x32_bf16(pf, vf, o[j], 0, 0, 0);
      }
    }
  }

#pragma unroll
  for (int r = 0; r < 4; r++) {
    float l = l_i[r];
#pragma unroll
    for (int off = 1; off < 16; off <<= 1) l += __shfl_xor(l, off);
    const float inv = 1.0f / l;
    const int row = q0 + wave * 16 + quad * 4 + r;
#pragma unroll
    for (int j = 0; j < 4; j++)
      Y[((size_t)b * T + row) * 1024 + h * 64 + j * 16 + l16] =
          (bf16_t)(o[j][r] * inv);
  }
}
#endif

// ---------------------------------------------------------------------------
extern "C" void kernel_launch(void* const* d_in, const int* in_sizes, int n_in,
                              void* d_out, int out_size, void* d_ws,
                              size_t ws_size, hipStream_t stream) {
  const float* x = nullptr;
  const float* w_qkv = nullptr;
  const float* b_qkv = nullptr;
  const float* w_out = nullptr;
  const float* b_out = nullptr;
  for (int i = 0; i < n_in; i++) {
    switch (in_sizes[i]) {
      case 4194304: x = (const float*)d_in[i]; break;
      case 3145728: w_qkv = (const float*)d_in[i]; break;
      case 3072:    b_qkv = (const float*)d_in[i]; break;
      case 1048576: w_out = (const float*)d_in[i]; break;
      case 1024:    b_out = (const float*)d_in[i]; break;
      default: break;
    }
  }
  float* out = (float*)d_out;  // FP32 output

  bf16_t* xb = (bf16_t*)d_ws;
  bf16_t* wqkvT = xb + (size_t)4194304;
  bf16_t* woutT = wqkvT + (size_t)3145728;
  bf16_t* qkv = woutT + (size_t)1048576;
  bf16_t* Y = qkv + (size_t)12582912;

  prep_kernel<<<6144, 256, 0, stream>>>(x, w_qkv, w_out, xb, wqkvT, woutT);
  gemm_bt_kernel<false><<<dim3(24, 32), 256, 0, stream>>>(
      xb, wqkvT, b_qkv, (void*)qkv, 4096, 3072, 1024);
  attn_kernel<<<dim3(32, 32), 256, 0, stream>>>(qkv, Y);
  gemm_bt64_kernel<<<dim3(8, 64), 256, 0, stream>>>(
      Y, woutT, b_out, out, 4096, 1024, 1024);
}

// Round 7
// 178.625 us; speedup vs baseline: 1.0946x; 1.0397x over previous
//
#include <hip/hip_runtime.h>
#include <hip/hip_bf16.h>
#include <stdint.h>

// SelfAttention B=2,T=2048,C=1024,H=16,hd=64. Inputs fp32, output fp32.
// R18: gemm1 -> BK=64 + XOR-swizzled LDS (T2 via per-lane scattered
// global_load_lds SOURCE, LDS dest linear — m173 pattern, same scheme as
// the proven attn sK swizzle). Halves barrier-drain events (32->16 iters,
// the 2-phase critical path per m233) and removes the 8-way ds_read bank
// conflict of the BK=32 layout (now 2-way = free). LDS 32 KB, occupancy
// unchanged (3 blk/CU, __launch_bounds__(256,3)).
// attn = R14 (proven 48us), gemm2 = bt64 (R17, proven), prep unchanged.

typedef __bf16 bf16_t;
typedef __attribute__((ext_vector_type(8))) __bf16 bf16x8;
typedef __attribute__((ext_vector_type(4))) __bf16 bf16x4;
typedef __attribute__((ext_vector_type(4))) short short4v;
typedef __attribute__((ext_vector_type(4))) float f32x4;

static_assert(sizeof(bf16x8) == 16, "bf16x8 must be 16B");

#if defined(__has_builtin)
#if __has_builtin(__builtin_amdgcn_mfma_f32_16x16x16bf16_1k)
#define HAVE_MFMA16 1
#endif
#if __has_builtin(__builtin_amdgcn_exp2f)
#define EXP2F(x) __builtin_amdgcn_exp2f(x)
#endif
#endif
#ifndef HAVE_MFMA16
#define HAVE_MFMA16 0
#endif
#ifndef EXP2F
#define EXP2F(x) exp2f(x)
#endif

// async global->LDS, 16B/lane. LDS dest = wave-uniform base + lane*16.
__device__ inline void async_copy16(const bf16_t* gsrc, bf16_t* lds_dst) {
  __builtin_amdgcn_global_load_lds(
      (const __attribute__((address_space(1))) uint32_t*)(const void*)gsrc,
      (__attribute__((address_space(3))) uint32_t*)(void*)lds_dst,
      16, 0, 0);
}

// ---------------------------------------------------------------------------
// Merged prep: blocks [0,2048) convx; [2048,5120) transpose w_qkv;
// [5120,6144) transpose w_out.
// ---------------------------------------------------------------------------
__global__ __launch_bounds__(256) void prep_kernel(
    const float* __restrict__ x, const float* __restrict__ wq,
    const float* __restrict__ wo, bf16_t* __restrict__ xb,
    bf16_t* __restrict__ wqkvT, bf16_t* __restrict__ woutT) {
  __shared__ bf16_t tile[32][33];
  const int bid = blockIdx.x;
  if (bid < 2048) {
    const int i = bid * 256 + threadIdx.x;  // < 524288
    const float4* s = (const float4*)x;
    float4 a = s[i * 2], b = s[i * 2 + 1];
    bf16x8 o;
    o[0] = (bf16_t)a.x; o[1] = (bf16_t)a.y; o[2] = (bf16_t)a.z; o[3] = (bf16_t)a.w;
    o[4] = (bf16_t)b.x; o[5] = (bf16_t)b.y; o[6] = (bf16_t)b.z; o[7] = (bf16_t)b.w;
    ((bf16x8*)xb)[i] = o;
    return;
  }
  const bool isq = bid < 5120;
  const int id = isq ? bid - 2048 : bid - 5120;
  const int C = isq ? 3072 : 1024;
  const int R = 1024;
  const int nbx = isq ? 96 : 32;
  const float* in = isq ? wq : wo;
  bf16_t* out = isq ? wqkvT : woutT;
  const int c0 = (id % nbx) * 32, r0 = (id / nbx) * 32;
  const int tx = threadIdx.x & 31;
  const int ty = threadIdx.x >> 5;
#pragma unroll
  for (int i = 0; i < 4; i++) {
    int r = ty + i * 8;
    tile[r][tx] = (bf16_t)in[(size_t)(r0 + r) * C + c0 + tx];
  }
  __syncthreads();
#pragma unroll
  for (int i = 0; i < 4; i++) {
    int r = ty + i * 8;
    out[(size_t)(c0 + r) * R + r0 + tx] = tile[tx][r];
  }
}

// ---------------------------------------------------------------------------
// C[M,N] = A[M,K] @ Bt[N,K]^T + bias[N]. bf16 in; OUT_F32 selects store type.
// BM=BN=128, BK=64, 4 waves 2x2. global_load_lds staging with per-lane
// pre-swizzled SOURCE (chunk cs = cl ^ rl), linear LDS dest; ds_read at
// chunk (h*4+quad)^(row&7) -> 2-way bank aliasing (free). 16 K-iters.
// ---------------------------------------------------------------------------
template <bool OUT_F32>
__global__ __launch_bounds__(256, 3) void gemm_bt_kernel(
    const bf16_t* __restrict__ A, const bf16_t* __restrict__ Bt,
    const float* __restrict__ bias, void* __restrict__ Cv, int M, int N,
    int K) {
  __shared__ __align__(16) bf16_t sA[128 * 64];  // 16 KB
  __shared__ __align__(16) bf16_t sB[128 * 64];  // 16 KB
  const int tid = threadIdx.x;
  const int wave = tid >> 6, lane = tid & 63;
  const int quad = lane >> 4, l16 = lane & 15;
  const int wm = (wave >> 1) * 64, wn = (wave & 1) * 64;
  const int bm = blockIdx.y * 128, bn = blockIdx.x * 128;

  // staging: wave covers rows [wave*32, wave*32+32), 4 calls x 8 rows.
  // lane: row-in-call rl = lane>>3, LDS chunk cl = lane&7 (16B chunks).
  // source chunk cs = cl ^ rl  (row&7 == rl since row ≡ rl mod 8).
  const int rl = lane >> 3, cl = lane & 7;
  const int srow = wave * 32;
  const bf16_t* gA =
      A + (size_t)(bm + srow + rl) * K + (size_t)((cl ^ rl) << 3);
  const bf16_t* gB =
      Bt + (size_t)(bn + srow + rl) * K + (size_t)((cl ^ rl) << 3);
  bf16_t* lA = sA + srow * 64;
  bf16_t* lB = sB + srow * 64;

  f32x4 acc[4][4] = {};

  for (int k0 = 0; k0 < K; k0 += 64) {
    __syncthreads();
#pragma unroll
    for (int c = 0; c < 4; c++) {
      async_copy16(gA + (size_t)(c * 8) * K + k0, lA + c * 512);
      async_copy16(gB + (size_t)(c * 8) * K + k0, lB + c * 512);
    }
    __syncthreads();

#pragma unroll
    for (int h = 0; h < 2; h++) {
      bf16x8 af[4], bfr[4];
#pragma unroll
      for (int i = 0; i < 4; i++) {
        const int row = wm + i * 16 + l16;
        af[i] = *(const bf16x8*)&sA[row * 64 +
                                    (((h * 4 + quad) ^ (row & 7)) << 3)];
      }
#pragma unroll
      for (int j = 0; j < 4; j++) {
        const int row = wn + j * 16 + l16;
        bfr[j] = *(const bf16x8*)&sB[row * 64 +
                                     (((h * 4 + quad) ^ (row & 7)) << 3)];
      }
#pragma unroll
      for (int i = 0; i < 4; i++)
#pragma unroll
        for (int j = 0; j < 4; j++)
          acc[i][j] = __builtin_amdgcn_mfma_f32_16x16x32_bf16(
              af[i], bfr[j], acc[i][j], 0, 0, 0);
    }
  }

#pragma unroll
  for (int j = 0; j < 4; j++) {
    const int col = bn + wn + j * 16 + l16;
    const float bv = bias[col];
#pragma unroll
    for (int i = 0; i < 4; i++) {
#pragma unroll
      for (int r = 0; r < 4; r++) {
        const int row = bm + wm + i * 16 + quad * 4 + r;
        const float v = acc[i][j][r] + bv;
        if (OUT_F32)
          ((float*)Cv)[(size_t)row * N + col] = v;
        else
          ((bf16_t*)Cv)[(size_t)row * N + col] = (bf16_t)v;
      }
    }
  }
}

// ---------------------------------------------------------------------------
// BM=64, BN=128 variant (f32 out) for gemm2: grid (N/128, M/64) = 512 blocks
// = 2 blocks/CU. Proven in R17. BK=32 m97-style staging.
// ---------------------------------------------------------------------------
__global__ __launch_bounds__(256) void gemm_bt64_kernel(
    const bf16_t* __restrict__ A, const bf16_t* __restrict__ Bt,
    const float* __restrict__ bias, float* __restrict__ C, int M, int N,
    int K) {
  __shared__ __align__(16) bf16_t sA[64 * 32];   // 4 KB
  __shared__ __align__(16) bf16_t sB[128 * 32];  // 8 KB
  const int tid = threadIdx.x;
  const int wave = tid >> 6, lane = tid & 63;
  const int quad = lane >> 4, l16 = lane & 15;
  const int wm = (wave >> 1) * 32, wn = (wave & 1) * 64;
  const int bm = blockIdx.y * 64, bn = blockIdx.x * 128;

  const int srow = wave * 16 + (lane >> 2);
  const int skk = (lane & 3) * 8;
  const bf16_t* gA = A + (size_t)(bm + srow) * K + skk;
  const bf16_t* gB = Bt + (size_t)(bn + srow) * K + skk;
  bf16_t* lA = sA + wave * 512;
  bf16_t* lB = sB + wave * 512;

  f32x4 acc[2][4] = {};

  for (int k0 = 0; k0 < K; k0 += 32) {
    __syncthreads();
    async_copy16(gA + k0, lA);                          // A rows [0,64)
    async_copy16(gB + k0, lB);                          // B rows [0,64)
    async_copy16(gB + (size_t)64 * K + k0, lB + 2048);  // B rows [64,128)
    __syncthreads();

    bf16x8 af[2], bfr[4];
#pragma unroll
    for (int i = 0; i < 2; i++)
      af[i] = *(const bf16x8*)&sA[(wm + i * 16 + l16) * 32 + quad * 8];
#pragma unroll
    for (int j = 0; j < 4; j++)
      bfr[j] = *(const bf16x8*)&sB[(wn + j * 16 + l16) * 32 + quad * 8];
#pragma unroll
    for (int i = 0; i < 2; i++)
#pragma unroll
      for (int j = 0; j < 4; j++)
        acc[i][j] = __builtin_amdgcn_mfma_f32_16x16x32_bf16(af[i], bfr[j],
                                                            acc[i][j], 0, 0, 0);
  }

#pragma unroll
  for (int j = 0; j < 4; j++) {
    const int col = bn + wn + j * 16 + l16;
    const float bv = bias[col];
#pragma unroll
    for (int i = 0; i < 2; i++) {
#pragma unroll
      for (int r = 0; r < 4; r++) {
        const int row = bm + wm + i * 16 + quad * 4 + r;
        C[(size_t)row * N + col] = acc[i][j][r] + bv;
      }
    }
  }
}

#if HAVE_MFMA16
// ---------------------------------------------------------------------------
// R14 attention (proven): S^T = K@Q^T (16x16x32), P stays in registers as
// the K=16 MFMA A-fragment; O += P@V via mfma_f32_16x16x16_bf16. Double-
// buffered sK/sVt, ONE barrier per 64-key tile. Fixed-M softmax.
// sK : (t,d) at t*64 + (((d>>3) ^ (t&7))<<3) + (d&7)        [8 KB/buf]
// sVt: (d,t) at d*64 + (((t>>2) ^ (d&15))<<2) + (t&3)       [8 KB/buf]
// Main loop = full tiles only (branchless); diagonal tile hoisted after.
// Balance: X remapped so each CU's 4 resident blocks have sum(X)==62.
// ---------------------------------------------------------------------------
__global__ __launch_bounds__(256, 4) void attn_kernel(
    const bf16_t* __restrict__ qkv, bf16_t* __restrict__ Y) {
  constexpr int T = 2048, C3 = 3072;
  constexpr float CSC = 0.18033688f;  // 0.125 * log2(e)
  constexpr float MB = 20.0f;
  __shared__ __align__(16) bf16_t sK[2][64 * 64];
  __shared__ __align__(16) bf16_t sVt[2][64 * 64];

  const int tid = threadIdx.x;
  const int wave = tid >> 6, lane = tid & 63;
  const int quad = lane >> 4, l16 = lane & 15;
  const int bh = blockIdx.y;
  // causal-depth balance remap (bijective in bx for each bh):
  const int flip = (bh >> 3) & 1;
  const int vv = ((int)blockIdx.x + ((bh >> 4) & 1) * 8) & 31;
  const int X = flip ? (31 - vv) : vv;
  const int q0 = X * 64;
  const int b = bh >> 4, h = bh & 15;
  const size_t base = (size_t)b * T * C3 + (size_t)h * 64;

  // Q as B-operand: lane n=l16=query, k = quad*8+j
  const int qrow = q0 + wave * 16 + l16;
  const bf16x8 qf0 = *(const bf16x8*)&qkv[base + (size_t)qrow * C3 + quad * 8];
  const bf16x8 qf1 =
      *(const bf16x8*)&qkv[base + (size_t)qrow * C3 + 32 + quad * 8];

  f32x4 o[4] = {};   // O: lane holds rows (query) quad*4+r, col d = n16*16+l16
  f32x4 l4 = {0.f, 0.f, 0.f, 0.f};  // 4 parallel partial-sum chains

  // K staging: (t = tid>>2 key row, seg = tid&3)
  const int t = tid >> 2, seg = tid & 3;
  const bf16_t* gK = &qkv[base + (size_t)t * C3 + 1024 + seg * 16];
  // V staging: (kq = tid>>4 key-quad, dq = tid&15 d-quad)
  const int kq = tid >> 4, dq = tid & 15;
  const bf16_t* gV = &qkv[base + (size_t)(4 * kq) * C3 + 2048 + dq * 4];

  bf16x8 kr0 = *(const bf16x8*)gK;
  bf16x8 kr1 = *(const bf16x8*)(gK + 8);
  bf16x4 vA0 = *(const bf16x4*)gV;
  bf16x4 vA1 = *(const bf16x4*)(gV + C3);
  bf16x4 vA2 = *(const bf16x4*)(gV + 2 * C3);
  bf16x4 vA3 = *(const bf16x4*)(gV + 3 * C3);

  // ---- main loop: tiles 0..X-1, all keys < all queries: branch-free ----
  for (int kt = 0; kt < X; kt++) {
    const int p = kt & 1;
    // stage K (2 b128, swizzled) and V (4 b64, key-quad granules)
    *(bf16x8*)&sK[p][t * 64 + (((2 * seg + 0) ^ (t & 7)) << 3)] = kr0;
    *(bf16x8*)&sK[p][t * 64 + (((2 * seg + 1) ^ (t & 7)) << 3)] = kr1;
#pragma unroll
    for (int i = 0; i < 4; i++) {
      const int d = dq * 4 + i;
      bf16x4 w;
      w[0] = vA0[i]; w[1] = vA1[i]; w[2] = vA2[i]; w[3] = vA3[i];
      *(bf16x4*)&sVt[p][d * 64 + ((kq ^ (d & 15)) << 2)] = w;
    }
    // prefetch next tile (kt+1 <= X always valid); overlaps compute
    {
      const size_t off = (size_t)(kt + 1) * 64 * C3;
      kr0 = *(const bf16x8*)(gK + off);
      kr1 = *(const bf16x8*)(gK + off + 8);
      vA0 = *(const bf16x4*)(gV + off);
      vA1 = *(const bf16x4*)(gV + off + C3);
      vA2 = *(const bf16x4*)(gV + off + 2 * C3);
      vA3 = *(const bf16x4*)(gV + off + 3 * C3);
    }
    __syncthreads();  // single barrier: buf p visible; buf 1-p free

#pragma unroll
    for (int j = 0; j < 4; j++) {
      // S^T j-tile: A = K-frag (lane m=l16 -> key j*16+l16), B = Q-frag
      const int trow = j * 16 + l16;
      bf16x8 kf0 =
          *(const bf16x8*)&sK[p][trow * 64 + ((quad ^ (trow & 7)) << 3)];
      bf16x8 kf1 =
          *(const bf16x8*)&sK[p][trow * 64 + (((4 + quad) ^ (trow & 7)) << 3)];
      f32x4 s2 = {};
      __builtin_amdgcn_s_setprio(1);
      s2 = __builtin_amdgcn_mfma_f32_16x16x32_bf16(kf0, qf0, s2, 0, 0, 0);
      s2 = __builtin_amdgcn_mfma_f32_16x16x32_bf16(kf1, qf1, s2, 0, 0, 0);
      __builtin_amdgcn_s_setprio(0);
#pragma unroll
      for (int r = 0; r < 4; r++) s2[r] = EXP2F(fmaf(s2[r], CSC, -MB));
      l4 += s2;  // 4 parallel chains
      bf16x4 pb;
      pb[0] = (bf16_t)s2[0]; pb[1] = (bf16_t)s2[1];
      pb[2] = (bf16_t)s2[2]; pb[3] = (bf16_t)s2[3];
      union { bf16x4 bv; short4v sv; } u;
      u.bv = pb;
      const short4v pa = u.sv;
      __builtin_amdgcn_s_setprio(1);
#pragma unroll
      for (int n16 = 0; n16 < 4; n16++) {
        const int d = n16 * 16 + l16;
        const short4v vf = *(const short4v*)&sVt[p][d * 64 +
                                                    (((j * 4 + quad) ^ (d & 15))
                                                     << 2)];
        o[n16] =
            __builtin_amdgcn_mfma_f32_16x16x16bf16_1k(pa, vf, o[n16], 0, 0, 0);
      }
      __builtin_amdgcn_s_setprio(0);
    }
  }

  // ---- diagonal tile kt == X (hoisted; j-skip + diag mask) ----
  {
    const int p = X & 1;
    *(bf16x8*)&sK[p][t * 64 + (((2 * seg + 0) ^ (t & 7)) << 3)] = kr0;
    *(bf16x8*)&sK[p][t * 64 + (((2 * seg + 1) ^ (t & 7)) << 3)] = kr1;
#pragma unroll
    for (int i = 0; i < 4; i++) {
      const int d = dq * 4 + i;
      bf16x4 w;
      w[0] = vA0[i]; w[1] = vA1[i]; w[2] = vA2[i]; w[3] = vA3[i];
      *(bf16x4*)&sVt[p][d * 64 + ((kq ^ (d & 15)) << 2)] = w;
    }
    __syncthreads();

#pragma unroll
    for (int j = 0; j < 4; j++) {
      if (j > wave) continue;  // wave-uniform; P would be all-zero
      const int trow = j * 16 + l16;
      bf16x8 kf0 =
          *(const bf16x8*)&sK[p][trow * 64 + ((quad ^ (trow & 7)) << 3)];
      bf16x8 kf1 =
          *(const bf16x8*)&sK[p][trow * 64 + (((4 + quad) ^ (trow & 7)) << 3)];
      f32x4 s2 = {};
      __builtin_amdgcn_s_setprio(1);
      s2 = __builtin_amdgcn_mfma_f32_16x16x32_bf16(kf0, qf0, s2, 0, 0, 0);
      s2 = __builtin_amdgcn_mfma_f32_16x16x32_bf16(kf1, qf1, s2, 0, 0, 0);
      __builtin_amdgcn_s_setprio(0);
      const bool diag = (j == wave);
#pragma unroll
      for (int r = 0; r < 4; r++) {
        float pv = EXP2F(fmaf(s2[r], CSC, -MB));
        if (diag && (quad * 4 + r > l16)) pv = 0.f;
        s2[r] = pv;
      }
      l4 += s2;
      bf16x4 pb;
      pb[0] = (bf16_t)s2[0]; pb[1] = (bf16_t)s2[1];
      pb[2] = (bf16_t)s2[2]; pb[3] = (bf16_t)s2[3];
      union { bf16x4 bv; short4v sv; } u;
      u.bv = pb;
      const short4v pa = u.sv;
      __builtin_amdgcn_s_setprio(1);
#pragma unroll
      for (int n16 = 0; n16 < 4; n16++) {
        const int d = n16 * 16 + l16;
        const short4v vf = *(const short4v*)&sVt[p][d * 64 +
                                                    (((j * 4 + quad) ^ (d & 15))
                                                     << 2)];
        o[n16] =
            __builtin_amdgcn_mfma_f32_16x16x16bf16_1k(pa, vf, o[n16], 0, 0, 0);
      }
      __builtin_amdgcn_s_setprio(0);
    }
  }

  // epilogue: complete l across quads (2 shuffles), redistribute, store
  float l_acc = (l4[0] + l4[1]) + (l4[2] + l4[3]);
  l_acc += __shfl_xor(l_acc, 16);
  l_acc += __shfl_xor(l_acc, 32);
#pragma unroll
  for (int r = 0; r < 4; r++) {
    const float lr = __shfl(l_acc, quad * 4 + r);
    const float inv = 1.0f / lr;
    const int row = q0 + wave * 16 + quad * 4 + r;
#pragma unroll
    for (int n16 = 0; n16 < 4; n16++)
      Y[((size_t)b * T + row) * 1024 + h * 64 + n16 * 16 + l16] =
          (bf16_t)(o[n16][r] * inv);
  }
}
#else
// ---------------------------------------------------------------------------
// Fallback = R10 attention (sP round-trip), with the R12 balance remap.
// ---------------------------------------------------------------------------
__global__ __launch_bounds__(256, 4) void attn_kernel(
    const bf16_t* __restrict__ qkv, bf16_t* __restrict__ Y) {
  constexpr int T = 2048, C3 = 3072;
  constexpr float CSC = 0.18033688f;
  constexpr float MB = 20.0f;
  __shared__ __align__(16) bf16_t sK[64 * 64];
  __shared__ __align__(16) bf16_t sVt[64 * 64];
  __shared__ __align__(16) bf16_t sP[4][16 * 64];

  const int tid = threadIdx.x;
  const int wave = tid >> 6, lane = tid & 63;
  const int quad = lane >> 4, l16 = lane & 15;
  const int bh = blockIdx.y;
  const int flip = (bh >> 3) & 1;
  const int vv = ((int)blockIdx.x + ((bh >> 4) & 1) * 8) & 31;
  const int X = flip ? (31 - vv) : vv;
  const int q0 = X * 64;
  const int b = bh >> 4, h = bh & 15;
  const size_t base = (size_t)b * T * C3 + (size_t)h * 64;

  const int qrow = q0 + wave * 16 + l16;
  const bf16x8 qf0 = *(const bf16x8*)&qkv[base + (size_t)qrow * C3 + quad * 8];
  const bf16x8 qf1 =
      *(const bf16x8*)&qkv[base + (size_t)qrow * C3 + 32 + quad * 8];

  f32x4 o[4] = {};
  float l_i[4] = {0.f, 0.f, 0.f, 0.f};

  const int t = tid >> 2, seg = tid & 3;
  const int tk = t & 7, tg3 = t >> 3;
  const bf16_t* gK = &qkv[base + (size_t)t * C3 + 1024 + seg * 16];
  const bf16_t* gV = &qkv[base + (size_t)t * C3 + 2048 + seg * 16];

  const int ktiles = X + 1;

  bf16x8 kr0 = *(const bf16x8*)gK;
  bf16x8 kr1 = *(const bf16x8*)(gK + 8);
  bf16x8 vr0 = *(const bf16x8*)gV;
  bf16x8 vr1 = *(const bf16x8*)(gV + 8);

  for (int kt = 0; kt < ktiles; kt++) {
    __syncthreads();
    *(bf16x8*)&sK[t * 64 + (((2 * seg + 0) ^ tk) << 3)] = kr0;
    *(bf16x8*)&sK[t * 64 + (((2 * seg + 1) ^ tk) << 3)] = kr1;
#pragma unroll
    for (int i = 0; i < 8; i++) {
      const int d = seg * 16 + i;
      sVt[d * 64 + ((tg3 ^ (d >> 3)) << 3) + (t & 7)] = vr0[i];
    }
#pragma unroll
    for (int i = 0; i < 8; i++) {
      const int d = seg * 16 + 8 + i;
      sVt[d * 64 + ((tg3 ^ (d >> 3)) << 3) + (t & 7)] = vr1[i];
    }
    __syncthreads();

    if (kt + 1 < ktiles) {
      const size_t off = (size_t)(kt + 1) * 64 * C3;
      kr0 = *(const bf16x8*)(gK + off);
      kr1 = *(const bf16x8*)(gK + off + 8);
      vr0 = *(const bf16x8*)(gV + off);
      vr1 = *(const bf16x8*)(gV + off + 8);
    }

    f32x4 s[4] = {};
#pragma unroll
    for (int j = 0; j < 4; j++) {
      const int kkey = l16 & 7;
      bf16x8 kf0 =
          *(const bf16x8*)&sK[(j * 16 + l16) * 64 + ((quad ^ kkey) << 3)];
      bf16x8 kf1 =
          *(const bf16x8*)&sK[(j * 16 + l16) * 64 + (((4 + quad) ^ kkey) << 3)];
      s[j] = __builtin_amdgcn_mfma_f32_16x16x32_bf16(qf0, kf0, s[j], 0, 0, 0);
      s[j] = __builtin_amdgcn_mfma_f32_16x16x32_bf16(qf1, kf1, s[j], 0, 0, 0);
    }

#pragma unroll
    for (int j = 0; j < 4; j++)
#pragma unroll
      for (int r = 0; r < 4; r++) s[j][r] = EXP2F(fmaf(s[j][r], CSC, -MB));
    if (kt == ktiles - 1) {
      const int k0 = kt * 64;
#pragma unroll
      for (int j = 0; j < 4; j++) {
        const int kcol = k0 + j * 16 + l16;
#pragma unroll
        for (int r = 0; r < 4; r++)
          if (kcol > q0 + wave * 16 + quad * 4 + r) s[j][r] = 0.f;
      }
    }
#pragma unroll
    for (int j = 0; j < 4; j++)
#pragma unroll
      for (int r = 0; r < 4; r++) l_i[r] += s[j][r];

    bf16_t* sp = &sP[wave][0];
#pragma unroll
    for (int j = 0; j < 4; j++)
#pragma unroll
      for (int r = 0; r < 4; r++) {
        const int m = quad * 4 + r;
        const int kw = (m + (m >> 3)) & 7;
        sp[m * 64 + ((((2 * j + (l16 >> 3)) ^ kw)) << 3) + (l16 & 7)] =
            (bf16_t)s[j][r];
      }

    const int kap = (l16 + (l16 >> 3)) & 7;
#pragma unroll
    for (int s2 = 0; s2 < 2; s2++) {
      bf16x8 pf =
          *(const bf16x8*)&sp[l16 * 64 + (((4 * s2 + quad) ^ kap) << 3)];
#pragma unroll
      for (int j = 0; j < 4; j++) {
        const int d = j * 16 + l16;
        bf16x8 vf =
            *(const bf16x8*)&sVt[d * 64 + (((4 * s2 + quad) ^ (d >> 3)) << 3)];
        o[j] = __builtin_amdgcn_mfma_f32_16x16x32_bf16(pf, vf, o[j], 0, 0, 0);
      }
    }
  }

#pragma unroll
  for (int r = 0; r < 4; r++) {
    float l = l_i[r];
#pragma unroll
    for (int off = 1; off < 16; off <<= 1) l += __shfl_xor(l, off);
    const float inv = 1.0f / l;
    const int row = q0 + wave * 16 + quad * 4 + r;
#pragma unroll
    for (int j = 0; j < 4; j++)
      Y[((size_t)b * T + row) * 1024 + h * 64 + j * 16 + l16] =
          (bf16_t)(o[j][r] * inv);
  }
}
#endif

// ---------------------------------------------------------------------------
extern "C" void kernel_launch(void* const* d_in, const int* in_sizes, int n_in,
                              void* d_out, int out_size, void* d_ws,
                              size_t ws_size, hipStream_t stream) {
  const float* x = nullptr;
  const float* w_qkv = nullptr;
  const float* b_qkv = nullptr;
  const float* w_out = nullptr;
  const float* b_out = nullptr;
  for (int i = 0; i < n_in; i++) {
    switch (in_sizes[i]) {
      case 4194304: x = (const float*)d_in[i]; break;
      case 3145728: w_qkv = (const float*)d_in[i]; break;
      case 3072:    b_qkv = (const float*)d_in[i]; break;
      case 1048576: w_out = (const float*)d_in[i]; break;
      case 1024:    b_out = (const float*)d_in[i]; break;
      default: break;
    }
  }
  float* out = (float*)d_out;  // FP32 output

  bf16_t* xb = (bf16_t*)d_ws;
  bf16_t* wqkvT = xb + (size_t)4194304;
  bf16_t* woutT = wqkvT + (size_t)3145728;
  bf16_t* qkv = woutT + (size_t)1048576;
  bf16_t* Y = qkv + (size_t)12582912;

  prep_kernel<<<6144, 256, 0, stream>>>(x, w_qkv, w_out, xb, wqkvT, woutT);
  gemm_bt_kernel<false><<<dim3(24, 32), 256, 0, stream>>>(
      xb, wqkvT, b_qkv, (void*)qkv, 4096, 3072, 1024);
  attn_kernel<<<dim3(32, 32), 256, 0, stream>>>(qkv, Y);
  gemm_bt64_kernel<<<dim3(8, 64), 256, 0, stream>>>(
      Y, woutT, b_out, out, 4096, 1024, 1024);
}

// Round 8
// 172.393 us; speedup vs baseline: 1.1342x; 1.0361x over previous
//
#include <hip/hip_runtime.h>
#include <hip/hip_bf16.h>
#include <stdint.h>

// SelfAttention B=2,T=2048,C=1024,H=16,hd=64. Inputs fp32, output fp32.
// R19: gemm2 ported to the R18 scheme — BK=64 + XOR-swizzled LDS via
// per-lane pre-swizzled global_load_lds SOURCE (linear LDS dest, m173).
// Halves gemm2's barrier-drain events (32->16) and removes its 8-way
// ds_read bank conflict (now 2-way = free). sA 8KB + sB 16KB = 24KB.
// gemm1 = R18 (proven), attn = R14 (proven, 32-tile makespan is the
// structural floor without split-K; split-K retired after two
// deterministic failures), prep unchanged.

typedef __bf16 bf16_t;
typedef __attribute__((ext_vector_type(8))) __bf16 bf16x8;
typedef __attribute__((ext_vector_type(4))) __bf16 bf16x4;
typedef __attribute__((ext_vector_type(4))) short short4v;
typedef __attribute__((ext_vector_type(4))) float f32x4;

static_assert(sizeof(bf16x8) == 16, "bf16x8 must be 16B");

#if defined(__has_builtin)
#if __has_builtin(__builtin_amdgcn_mfma_f32_16x16x16bf16_1k)
#define HAVE_MFMA16 1
#endif
#if __has_builtin(__builtin_amdgcn_exp2f)
#define EXP2F(x) __builtin_amdgcn_exp2f(x)
#endif
#endif
#ifndef HAVE_MFMA16
#define HAVE_MFMA16 0
#endif
#ifndef EXP2F
#define EXP2F(x) exp2f(x)
#endif

// async global->LDS, 16B/lane. LDS dest = wave-uniform base + lane*16.
__device__ inline void async_copy16(const bf16_t* gsrc, bf16_t* lds_dst) {
  __builtin_amdgcn_global_load_lds(
      (const __attribute__((address_space(1))) uint32_t*)(const void*)gsrc,
      (__attribute__((address_space(3))) uint32_t*)(void*)lds_dst,
      16, 0, 0);
}

// ---------------------------------------------------------------------------
// Merged prep: blocks [0,2048) convx; [2048,5120) transpose w_qkv;
// [5120,6144) transpose w_out.
// ---------------------------------------------------------------------------
__global__ __launch_bounds__(256) void prep_kernel(
    const float* __restrict__ x, const float* __restrict__ wq,
    const float* __restrict__ wo, bf16_t* __restrict__ xb,
    bf16_t* __restrict__ wqkvT, bf16_t* __restrict__ woutT) {
  __shared__ bf16_t tile[32][33];
  const int bid = blockIdx.x;
  if (bid < 2048) {
    const int i = bid * 256 + threadIdx.x;  // < 524288
    const float4* s = (const float4*)x;
    float4 a = s[i * 2], b = s[i * 2 + 1];
    bf16x8 o;
    o[0] = (bf16_t)a.x; o[1] = (bf16_t)a.y; o[2] = (bf16_t)a.z; o[3] = (bf16_t)a.w;
    o[4] = (bf16_t)b.x; o[5] = (bf16_t)b.y; o[6] = (bf16_t)b.z; o[7] = (bf16_t)b.w;
    ((bf16x8*)xb)[i] = o;
    return;
  }
  const bool isq = bid < 5120;
  const int id = isq ? bid - 2048 : bid - 5120;
  const int C = isq ? 3072 : 1024;
  const int R = 1024;
  const int nbx = isq ? 96 : 32;
  const float* in = isq ? wq : wo;
  bf16_t* out = isq ? wqkvT : woutT;
  const int c0 = (id % nbx) * 32, r0 = (id / nbx) * 32;
  const int tx = threadIdx.x & 31;
  const int ty = threadIdx.x >> 5;
#pragma unroll
  for (int i = 0; i < 4; i++) {
    int r = ty + i * 8;
    tile[r][tx] = (bf16_t)in[(size_t)(r0 + r) * C + c0 + tx];
  }
  __syncthreads();
#pragma unroll
  for (int i = 0; i < 4; i++) {
    int r = ty + i * 8;
    out[(size_t)(c0 + r) * R + r0 + tx] = tile[tx][r];
  }
}

// ---------------------------------------------------------------------------
// C[M,N] = A[M,K] @ Bt[N,K]^T + bias[N]. bf16 in; OUT_F32 selects store type.
// BM=BN=128, BK=64, 4 waves 2x2. global_load_lds staging with per-lane
// pre-swizzled SOURCE (chunk cs = cl ^ rl), linear LDS dest; ds_read at
// chunk (h*4+quad)^(row&7) -> 2-way bank aliasing (free). 16 K-iters. (R18)
// ---------------------------------------------------------------------------
template <bool OUT_F32>
__global__ __launch_bounds__(256, 3) void gemm_bt_kernel(
    const bf16_t* __restrict__ A, const bf16_t* __restrict__ Bt,
    const float* __restrict__ bias, void* __restrict__ Cv, int M, int N,
    int K) {
  __shared__ __align__(16) bf16_t sA[128 * 64];  // 16 KB
  __shared__ __align__(16) bf16_t sB[128 * 64];  // 16 KB
  const int tid = threadIdx.x;
  const int wave = tid >> 6, lane = tid & 63;
  const int quad = lane >> 4, l16 = lane & 15;
  const int wm = (wave >> 1) * 64, wn = (wave & 1) * 64;
  const int bm = blockIdx.y * 128, bn = blockIdx.x * 128;

  // staging: wave covers rows [wave*32, wave*32+32), 4 calls x 8 rows.
  // lane: row-in-call rl = lane>>3, LDS chunk cl = lane&7 (16B chunks).
  // source chunk cs = cl ^ rl  (row&7 == rl since row ≡ rl mod 8).
  const int rl = lane >> 3, cl = lane & 7;
  const int srow = wave * 32;
  const bf16_t* gA =
      A + (size_t)(bm + srow + rl) * K + (size_t)((cl ^ rl) << 3);
  const bf16_t* gB =
      Bt + (size_t)(bn + srow + rl) * K + (size_t)((cl ^ rl) << 3);
  bf16_t* lA = sA + srow * 64;
  bf16_t* lB = sB + srow * 64;

  f32x4 acc[4][4] = {};

  for (int k0 = 0; k0 < K; k0 += 64) {
    __syncthreads();
#pragma unroll
    for (int c = 0; c < 4; c++) {
      async_copy16(gA + (size_t)(c * 8) * K + k0, lA + c * 512);
      async_copy16(gB + (size_t)(c * 8) * K + k0, lB + c * 512);
    }
    __syncthreads();

#pragma unroll
    for (int h = 0; h < 2; h++) {
      bf16x8 af[4], bfr[4];
#pragma unroll
      for (int i = 0; i < 4; i++) {
        const int row = wm + i * 16 + l16;
        af[i] = *(const bf16x8*)&sA[row * 64 +
                                    (((h * 4 + quad) ^ (row & 7)) << 3)];
      }
#pragma unroll
      for (int j = 0; j < 4; j++) {
        const int row = wn + j * 16 + l16;
        bfr[j] = *(const bf16x8*)&sB[row * 64 +
                                     (((h * 4 + quad) ^ (row & 7)) << 3)];
      }
#pragma unroll
      for (int i = 0; i < 4; i++)
#pragma unroll
        for (int j = 0; j < 4; j++)
          acc[i][j] = __builtin_amdgcn_mfma_f32_16x16x32_bf16(
              af[i], bfr[j], acc[i][j], 0, 0, 0);
    }
  }

#pragma unroll
  for (int j = 0; j < 4; j++) {
    const int col = bn + wn + j * 16 + l16;
    const float bv = bias[col];
#pragma unroll
    for (int i = 0; i < 4; i++) {
#pragma unroll
      for (int r = 0; r < 4; r++) {
        const int row = bm + wm + i * 16 + quad * 4 + r;
        const float v = acc[i][j][r] + bv;
        if (OUT_F32)
          ((float*)Cv)[(size_t)row * N + col] = v;
        else
          ((bf16_t*)Cv)[(size_t)row * N + col] = (bf16_t)v;
      }
    }
  }
}

// ---------------------------------------------------------------------------
// gemm2: BM=64, BN=128, BK=64 (f32 out), R18 swizzle scheme. Grid
// (N/128, M/64) = 512 blocks = 2 blocks/CU. sA 8KB + sB 16KB = 24KB.
// A staged 2 calls/wave (16 rows), B 4 calls/wave (32 rows). 16 K-iters.
// ---------------------------------------------------------------------------
__global__ __launch_bounds__(256) void gemm_bt64_kernel(
    const bf16_t* __restrict__ A, const bf16_t* __restrict__ Bt,
    const float* __restrict__ bias, float* __restrict__ C, int M, int N,
    int K) {
  __shared__ __align__(16) bf16_t sA[64 * 64];   // 8 KB
  __shared__ __align__(16) bf16_t sB[128 * 64];  // 16 KB
  const int tid = threadIdx.x;
  const int wave = tid >> 6, lane = tid & 63;
  const int quad = lane >> 4, l16 = lane & 15;
  const int wm = (wave >> 1) * 32, wn = (wave & 1) * 64;
  const int bm = blockIdx.y * 64, bn = blockIdx.x * 128;

  const int rl = lane >> 3, cl = lane & 7;
  // A: wave covers rows [wave*16, wave*16+16), 2 calls x 8 rows.
  const bf16_t* gA =
      A + (size_t)(bm + wave * 16 + rl) * K + (size_t)((cl ^ rl) << 3);
  bf16_t* lA = sA + (wave * 16) * 64;
  // B: wave covers rows [wave*32, wave*32+32), 4 calls x 8 rows.
  const bf16_t* gB =
      Bt + (size_t)(bn + wave * 32 + rl) * K + (size_t)((cl ^ rl) << 3);
  bf16_t* lB = sB + (wave * 32) * 64;

  f32x4 acc[2][4] = {};

  for (int k0 = 0; k0 < K; k0 += 64) {
    __syncthreads();
#pragma unroll
    for (int c = 0; c < 2; c++)
      async_copy16(gA + (size_t)(c * 8) * K + k0, lA + c * 512);
#pragma unroll
    for (int c = 0; c < 4; c++)
      async_copy16(gB + (size_t)(c * 8) * K + k0, lB + c * 512);
    __syncthreads();

#pragma unroll
    for (int h = 0; h < 2; h++) {
      bf16x8 af[2], bfr[4];
#pragma unroll
      for (int i = 0; i < 2; i++) {
        const int row = wm + i * 16 + l16;
        af[i] = *(const bf16x8*)&sA[row * 64 +
                                    (((h * 4 + quad) ^ (row & 7)) << 3)];
      }
#pragma unroll
      for (int j = 0; j < 4; j++) {
        const int row = wn + j * 16 + l16;
        bfr[j] = *(const bf16x8*)&sB[row * 64 +
                                     (((h * 4 + quad) ^ (row & 7)) << 3)];
      }
#pragma unroll
      for (int i = 0; i < 2; i++)
#pragma unroll
        for (int j = 0; j < 4; j++)
          acc[i][j] = __builtin_amdgcn_mfma_f32_16x16x32_bf16(
              af[i], bfr[j], acc[i][j], 0, 0, 0);
    }
  }

#pragma unroll
  for (int j = 0; j < 4; j++) {
    const int col = bn + wn + j * 16 + l16;
    const float bv = bias[col];
#pragma unroll
    for (int i = 0; i < 2; i++) {
#pragma unroll
      for (int r = 0; r < 4; r++) {
        const int row = bm + wm + i * 16 + quad * 4 + r;
        C[(size_t)row * N + col] = acc[i][j][r] + bv;
      }
    }
  }
}

#if HAVE_MFMA16
// ---------------------------------------------------------------------------
// R14 attention (proven): S^T = K@Q^T (16x16x32), P stays in registers as
// the K=16 MFMA A-fragment; O += P@V via mfma_f32_16x16x16_bf16. Double-
// buffered sK/sVt, ONE barrier per 64-key tile. Fixed-M softmax.
// sK : (t,d) at t*64 + (((d>>3) ^ (t&7))<<3) + (d&7)        [8 KB/buf]
// sVt: (d,t) at d*64 + (((t>>2) ^ (d&15))<<2) + (t&3)       [8 KB/buf]
// Main loop = full tiles only (branchless); diagonal tile hoisted after.
// Balance: X remapped so each CU's 4 resident blocks have sum(X)==62.
// ---------------------------------------------------------------------------
__global__ __launch_bounds__(256, 4) void attn_kernel(
    const bf16_t* __restrict__ qkv, bf16_t* __restrict__ Y) {
  constexpr int T = 2048, C3 = 3072;
  constexpr float CSC = 0.18033688f;  // 0.125 * log2(e)
  constexpr float MB = 20.0f;
  __shared__ __align__(16) bf16_t sK[2][64 * 64];
  __shared__ __align__(16) bf16_t sVt[2][64 * 64];

  const int tid = threadIdx.x;
  const int wave = tid >> 6, lane = tid & 63;
  const int quad = lane >> 4, l16 = lane & 15;
  const int bh = blockIdx.y;
  // causal-depth balance remap (bijective in bx for each bh):
  const int flip = (bh >> 3) & 1;
  const int vv = ((int)blockIdx.x + ((bh >> 4) & 1) * 8) & 31;
  const int X = flip ? (31 - vv) : vv;
  const int q0 = X * 64;
  const int b = bh >> 4, h = bh & 15;
  const size_t base = (size_t)b * T * C3 + (size_t)h * 64;

  // Q as B-operand: lane n=l16=query, k = quad*8+j
  const int qrow = q0 + wave * 16 + l16;
  const bf16x8 qf0 = *(const bf16x8*)&qkv[base + (size_t)qrow * C3 + quad * 8];
  const bf16x8 qf1 =
      *(const bf16x8*)&qkv[base + (size_t)qrow * C3 + 32 + quad * 8];

  f32x4 o[4] = {};   // O: lane holds rows (query) quad*4+r, col d = n16*16+l16
  f32x4 l4 = {0.f, 0.f, 0.f, 0.f};  // 4 parallel partial-sum chains

  // K staging: (t = tid>>2 key row, seg = tid&3)
  const int t = tid >> 2, seg = tid & 3;
  const bf16_t* gK = &qkv[base + (size_t)t * C3 + 1024 + seg * 16];
  // V staging: (kq = tid>>4 key-quad, dq = tid&15 d-quad)
  const int kq = tid >> 4, dq = tid & 15;
  const bf16_t* gV = &qkv[base + (size_t)(4 * kq) * C3 + 2048 + dq * 4];

  bf16x8 kr0 = *(const bf16x8*)gK;
  bf16x8 kr1 = *(const bf16x8*)(gK + 8);
  bf16x4 vA0 = *(const bf16x4*)gV;
  bf16x4 vA1 = *(const bf16x4*)(gV + C3);
  bf16x4 vA2 = *(const bf16x4*)(gV + 2 * C3);
  bf16x4 vA3 = *(const bf16x4*)(gV + 3 * C3);

  // ---- main loop: tiles 0..X-1, all keys < all queries: branch-free ----
  for (int kt = 0; kt < X; kt++) {
    const int p = kt & 1;
    // stage K (2 b128, swizzled) and V (4 b64, key-quad granules)
    *(bf16x8*)&sK[p][t * 64 + (((2 * seg + 0) ^ (t & 7)) << 3)] = kr0;
    *(bf16x8*)&sK[p][t * 64 + (((2 * seg + 1) ^ (t & 7)) << 3)] = kr1;
#pragma unroll
    for (int i = 0; i < 4; i++) {
      const int d = dq * 4 + i;
      bf16x4 w;
      w[0] = vA0[i]; w[1] = vA1[i]; w[2] = vA2[i]; w[3] = vA3[i];
      *(bf16x4*)&sVt[p][d * 64 + ((kq ^ (d & 15)) << 2)] = w;
    }
    // prefetch next tile (kt+1 <= X always valid); overlaps compute
    {
      const size_t off = (size_t)(kt + 1) * 64 * C3;
      kr0 = *(const bf16x8*)(gK + off);
      kr1 = *(const bf16x8*)(gK + off + 8);
      vA0 = *(const bf16x4*)(gV + off);
      vA1 = *(const bf16x4*)(gV + off + C3);
      vA2 = *(const bf16x4*)(gV + off + 2 * C3);
      vA3 = *(const bf16x4*)(gV + off + 3 * C3);
    }
    __syncthreads();  // single barrier: buf p visible; buf 1-p free

#pragma unroll
    for (int j = 0; j < 4; j++) {
      // S^T j-tile: A = K-frag (lane m=l16 -> key j*16+l16), B = Q-frag
      const int trow = j * 16 + l16;
      bf16x8 kf0 =
          *(const bf16x8*)&sK[p][trow * 64 + ((quad ^ (trow & 7)) << 3)];
      bf16x8 kf1 =
          *(const bf16x8*)&sK[p][trow * 64 + (((4 + quad) ^ (trow & 7)) << 3)];
      f32x4 s2 = {};
      __builtin_amdgcn_s_setprio(1);
      s2 = __builtin_amdgcn_mfma_f32_16x16x32_bf16(kf0, qf0, s2, 0, 0, 0);
      s2 = __builtin_amdgcn_mfma_f32_16x16x32_bf16(kf1, qf1, s2, 0, 0, 0);
      __builtin_amdgcn_s_setprio(0);
#pragma unroll
      for (int r = 0; r < 4; r++) s2[r] = EXP2F(fmaf(s2[r], CSC, -MB));
      l4 += s2;  // 4 parallel chains
      bf16x4 pb;
      pb[0] = (bf16_t)s2[0]; pb[1] = (bf16_t)s2[1];
      pb[2] = (bf16_t)s2[2]; pb[3] = (bf16_t)s2[3];
      union { bf16x4 bv; short4v sv; } u;
      u.bv = pb;
      const short4v pa = u.sv;
      __builtin_amdgcn_s_setprio(1);
#pragma unroll
      for (int n16 = 0; n16 < 4; n16++) {
        const int d = n16 * 16 + l16;
        const short4v vf = *(const short4v*)&sVt[p][d * 64 +
                                                    (((j * 4 + quad) ^ (d & 15))
                                                     << 2)];
        o[n16] =
            __builtin_amdgcn_mfma_f32_16x16x16bf16_1k(pa, vf, o[n16], 0, 0, 0);
      }
      __builtin_amdgcn_s_setprio(0);
    }
  }

  // ---- diagonal tile kt == X (hoisted; j-skip + diag mask) ----
  {
    const int p = X & 1;
    *(bf16x8*)&sK[p][t * 64 + (((2 * seg + 0) ^ (t & 7)) << 3)] = kr0;
    *(bf16x8*)&sK[p][t * 64 + (((2 * seg + 1) ^ (t & 7)) << 3)] = kr1;
#pragma unroll
    for (int i = 0; i < 4; i++) {
      const int d = dq * 4 + i;
      bf16x4 w;
      w[0] = vA0[i]; w[1] = vA1[i]; w[2] = vA2[i]; w[3] = vA3[i];
      *(bf16x4*)&sVt[p][d * 64 + ((kq ^ (d & 15)) << 2)] = w;
    }
    __syncthreads();

#pragma unroll
    for (int j = 0; j < 4; j++) {
      if (j > wave) continue;  // wave-uniform; P would be all-zero
      const int trow = j * 16 + l16;
      bf16x8 kf0 =
          *(const bf16x8*)&sK[p][trow * 64 + ((quad ^ (trow & 7)) << 3)];
      bf16x8 kf1 =
          *(const bf16x8*)&sK[p][trow * 64 + (((4 + quad) ^ (trow & 7)) << 3)];
      f32x4 s2 = {};
      __builtin_amdgcn_s_setprio(1);
      s2 = __builtin_amdgcn_mfma_f32_16x16x32_bf16(kf0, qf0, s2, 0, 0, 0);
      s2 = __builtin_amdgcn_mfma_f32_16x16x32_bf16(kf1, qf1, s2, 0, 0, 0);
      __builtin_amdgcn_s_setprio(0);
      const bool diag = (j == wave);
#pragma unroll
      for (int r = 0; r < 4; r++) {
        float pv = EXP2F(fmaf(s2[r], CSC, -MB));
        if (diag && (quad * 4 + r > l16)) pv = 0.f;
        s2[r] = pv;
      }
      l4 += s2;
      bf16x4 pb;
      pb[0] = (bf16_t)s2[0]; pb[1] = (bf16_t)s2[1];
      pb[2] = (bf16_t)s2[2]; pb[3] = (bf16_t)s2[3];
      union { bf16x4 bv; short4v sv; } u;
      u.bv = pb;
      const short4v pa = u.sv;
      __builtin_amdgcn_s_setprio(1);
#pragma unroll
      for (int n16 = 0; n16 < 4; n16++) {
        const int d = n16 * 16 + l16;
        const short4v vf = *(const short4v*)&sVt[p][d * 64 +
                                                    (((j * 4 + quad) ^ (d & 15))
                                                     << 2)];
        o[n16] =
            __builtin_amdgcn_mfma_f32_16x16x16bf16_1k(pa, vf, o[n16], 0, 0, 0);
      }
      __builtin_amdgcn_s_setprio(0);
    }
  }

  // epilogue: complete l across quads (2 shuffles), redistribute, store
  float l_acc = (l4[0] + l4[1]) + (l4[2] + l4[3]);
  l_acc += __shfl_xor(l_acc, 16);
  l_acc += __shfl_xor(l_acc, 32);
#pragma unroll
  for (int r = 0; r < 4; r++) {
    const float lr = __shfl(l_acc, quad * 4 + r);
    const float inv = 1.0f / lr;
    const int row = q0 + wave * 16 + quad * 4 + r;
#pragma unroll
    for (int n16 = 0; n16 < 4; n16++)
      Y[((size_t)b * T + row) * 1024 + h * 64 + n16 * 16 + l16] =
          (bf16_t)(o[n16][r] * inv);
  }
}
#else
// ---------------------------------------------------------------------------
// Fallback = R10 attention (sP round-trip), with the R12 balance remap.
// ---------------------------------------------------------------------------
__global__ __launch_bounds__(256, 4) void attn_kernel(
    const bf16_t* __restrict__ qkv, bf16_t* __restrict__ Y) {
  constexpr int T = 2048, C3 = 3072;
  constexpr float CSC = 0.18033688f;
  constexpr float MB = 20.0f;
  __shared__ __align__(16) bf16_t sK[64 * 64];
  __shared__ __align__(16) bf16_t sVt[64 * 64];
  __shared__ __align__(16) bf16_t sP[4][16 * 64];

  const int tid = threadIdx.x;
  const int wave = tid >> 6, lane = tid & 63;
  const int quad = lane >> 4, l16 = lane & 15;
  const int bh = blockIdx.y;
  const int flip = (bh >> 3) & 1;
  const int vv = ((int)blockIdx.x + ((bh >> 4) & 1) * 8) & 31;
  const int X = flip ? (31 - vv) : vv;
  const int q0 = X * 64;
  const int b = bh >> 4, h = bh & 15;
  const size_t base = (size_t)b * T * C3 + (size_t)h * 64;

  const int qrow = q0 + wave * 16 + l16;
  const bf16x8 qf0 = *(const bf16x8*)&qkv[base + (size_t)qrow * C3 + quad * 8];
  const bf16x8 qf1 =
      *(const bf16x8*)&qkv[base + (size_t)qrow * C3 + 32 + quad * 8];

  f32x4 o[4] = {};
  float l_i[4] = {0.f, 0.f, 0.f, 0.f};

  const int t = tid >> 2, seg = tid & 3;
  const int tk = t & 7, tg3 = t >> 3;
  const bf16_t* gK = &qkv[base + (size_t)t * C3 + 1024 + seg * 16];
  const bf16_t* gV = &qkv[base + (size_t)t * C3 + 2048 + seg * 16];

  const int ktiles = X + 1;

  bf16x8 kr0 = *(const bf16x8*)gK;
  bf16x8 kr1 = *(const bf16x8*)(gK + 8);
  bf16x8 vr0 = *(const bf16x8*)gV;
  bf16x8 vr1 = *(const bf16x8*)(gV + 8);

  for (int kt = 0; kt < ktiles; kt++) {
    __syncthreads();
    *(bf16x8*)&sK[t * 64 + (((2 * seg + 0) ^ tk) << 3)] = kr0;
    *(bf16x8*)&sK[t * 64 + (((2 * seg + 1) ^ tk) << 3)] = kr1;
#pragma unroll
    for (int i = 0; i < 8; i++) {
      const int d = seg * 16 + i;
      sVt[d * 64 + ((tg3 ^ (d >> 3)) << 3) + (t & 7)] = vr0[i];
    }
#pragma unroll
    for (int i = 0; i < 8; i++) {
      const int d = seg * 16 + 8 + i;
      sVt[d * 64 + ((tg3 ^ (d >> 3)) << 3) + (t & 7)] = vr1[i];
    }
    __syncthreads();

    if (kt + 1 < ktiles) {
      const size_t off = (size_t)(kt + 1) * 64 * C3;
      kr0 = *(const bf16x8*)(gK + off);
      kr1 = *(const bf16x8*)(gK + off + 8);
      vr0 = *(const bf16x8*)(gV + off);
      vr1 = *(const bf16x8*)(gV + off + 8);
    }

    f32x4 s[4] = {};
#pragma unroll
    for (int j = 0; j < 4; j++) {
      const int kkey = l16 & 7;
      bf16x8 kf0 =
          *(const bf16x8*)&sK[(j * 16 + l16) * 64 + ((quad ^ kkey) << 3)];
      bf16x8 kf1 =
          *(const bf16x8*)&sK[(j * 16 + l16) * 64 + (((4 + quad) ^ kkey) << 3)];
      s[j] = __builtin_amdgcn_mfma_f32_16x16x32_bf16(qf0, kf0, s[j], 0, 0, 0);
      s[j] = __builtin_amdgcn_mfma_f32_16x16x32_bf16(qf1, kf1, s[j], 0, 0, 0);
    }

#pragma unroll
    for (int j = 0; j < 4; j++)
#pragma unroll
      for (int r = 0; r < 4; r++) s[j][r] = EXP2F(fmaf(s[j][r], CSC, -MB));
    if (kt == ktiles - 1) {
      const int k0 = kt * 64;
#pragma unroll
      for (int j = 0; j < 4; j++) {
        const int kcol = k0 + j * 16 + l16;
#pragma unroll
        for (int r = 0; r < 4; r++)
          if (kcol > q0 + wave * 16 + quad * 4 + r) s[j][r] = 0.f;
      }
    }
#pragma unroll
    for (int j = 0; j < 4; j++)
#pragma unroll
      for (int r = 0; r < 4; r++) l_i[r] += s[j][r];

    bf16_t* sp = &sP[wave][0];
#pragma unroll
    for (int j = 0; j < 4; j++)
#pragma unroll
      for (int r = 0; r < 4; r++) {
        const int m = quad * 4 + r;
        const int kw = (m + (m >> 3)) & 7;
        sp[m * 64 + ((((2 * j + (l16 >> 3)) ^ kw)) << 3) + (l16 & 7)] =
            (bf16_t)s[j][r];
      }

    const int kap = (l16 + (l16 >> 3)) & 7;
#pragma unroll
    for (int s2 = 0; s2 < 2; s2++) {
      bf16x8 pf =
          *(const bf16x8*)&sp[l16 * 64 + (((4 * s2 + quad) ^ kap) << 3)];
#pragma unroll
      for (int j = 0; j < 4; j++) {
        const int d = j * 16 + l16;
        bf16x8 vf =
            *(const bf16x8*)&sVt[d * 64 + (((4 * s2 + quad) ^ (d >> 3)) << 3)];
        o[j] = __builtin_amdgcn_mfma_f32_16x16x32_bf16(pf, vf, o[j], 0, 0, 0);
      }
    }
  }

#pragma unroll
  for (int r = 0; r < 4; r++) {
    float l = l_i[r];
#pragma unroll
    for (int off = 1; off < 16; off <<= 1) l += __shfl_xor(l, off);
    const float inv = 1.0f / l;
    const int row = q0 + wave * 16 + quad * 4 + r;
#pragma unroll
    for (int j = 0; j < 4; j++)
      Y[((size_t)b * T + row) * 1024 + h * 64 + j * 16 + l16] =
          (bf16_t)(o[j][r] * inv);
  }
}
#endif

// ---------------------------------------------------------------------------
extern "C" void kernel_launch(void* const* d_in, const int* in_sizes, int n_in,
                              void* d_out, int out_size, void* d_ws,
                              size_t ws_size, hipStream_t stream) {
  const float* x = nullptr;
  const float* w_qkv = nullptr;
  const float* b_qkv = nullptr;
  const float* w_out = nullptr;
  const float* b_out = nullptr;
  for (int i = 0; i < n_in; i++) {
    switch (in_sizes[i]) {
      case 4194304: x = (const float*)d_in[i]; break;
      case 3145728: w_qkv = (const float*)d_in[i]; break;
      case 3072:    b_qkv = (const float*)d_in[i]; break;
      case 1048576: w_out = (const float*)d_in[i]; break;
      case 1024:    b_out = (const float*)d_in[i]; break;
      default: break;
    }
  }
  float* out = (float*)d_out;  // FP32 output

  bf16_t* xb = (bf16_t*)d_ws;
  bf16_t* wqkvT = xb + (size_t)4194304;
  bf16_t* woutT = wqkvT + (size_t)3145728;
  bf16_t* qkv = woutT + (size_t)1048576;
  bf16_t* Y = qkv + (size_t)12582912;

  prep_kernel<<<6144, 256, 0, stream>>>(x, w_qkv, w_out, xb, wqkvT, woutT);
  gemm_bt_kernel<false><<<dim3(24, 32), 256, 0, stream>>>(
      xb, wqkvT, b_qkv, (void*)qkv, 4096, 3072, 1024);
  attn_kernel<<<dim3(32, 32), 256, 0, stream>>>(qkv, Y);
  gemm_bt64_kernel<<<dim3(8, 64), 256, 0, stream>>>(
      Y, woutT, b_out, out, 4096, 1024, 1024);
}

// Round 10
// 171.873 us; speedup vs baseline: 1.1376x; 1.0030x over previous
//
#include <hip/hip_runtime.h>
#include <hip/hip_bf16.h>
#include <stdint.h>

// SelfAttention B=2,T=2048,C=1024,H=16,hd=64. Inputs fp32, output fp32.
// R21: revert R20's 8-wave attn (3rd attn-restructure correctness failure,
// absmax 3.6 ~ missing partial-merge; bug not locatable by inspection ->
// R14 attn frozen as proven). Config = R19 (172.4us passing: gemm1=R18
// BK=64+swz, gemm2=R19 BK=64+swz, attn=R14) + prep transpose vectorized:
// float4 reads (16B/lane) + ushort4 bf16 writes (8B/lane) vs scalar 4B/2B
// (G13 / Common-mistake #2 — 4x fewer mem instructions both sides).

typedef __bf16 bf16_t;
typedef __attribute__((ext_vector_type(8))) __bf16 bf16x8;
typedef __attribute__((ext_vector_type(4))) __bf16 bf16x4;
typedef __attribute__((ext_vector_type(4))) short short4v;
typedef __attribute__((ext_vector_type(4))) float f32x4;

static_assert(sizeof(bf16x8) == 16, "bf16x8 must be 16B");

#if defined(__has_builtin)
#if __has_builtin(__builtin_amdgcn_mfma_f32_16x16x16bf16_1k)
#define HAVE_MFMA16 1
#endif
#if __has_builtin(__builtin_amdgcn_exp2f)
#define EXP2F(x) __builtin_amdgcn_exp2f(x)
#endif
#endif
#ifndef HAVE_MFMA16
#define HAVE_MFMA16 0
#endif
#ifndef EXP2F
#define EXP2F(x) exp2f(x)
#endif

// async global->LDS, 16B/lane. LDS dest = wave-uniform base + lane*16.
__device__ inline void async_copy16(const bf16_t* gsrc, bf16_t* lds_dst) {
  __builtin_amdgcn_global_load_lds(
      (const __attribute__((address_space(1))) uint32_t*)(const void*)gsrc,
      (__attribute__((address_space(3))) uint32_t*)(void*)lds_dst,
      16, 0, 0);
}

// ---------------------------------------------------------------------------
// Merged prep: blocks [0,2048) convx; [2048,5120) transpose w_qkv;
// [5120,6144) transpose w_out. Transpose: float4 read, ushort4 bf16 write.
// ---------------------------------------------------------------------------
__global__ __launch_bounds__(256) void prep_kernel(
    const float* __restrict__ x, const float* __restrict__ wq,
    const float* __restrict__ wo, bf16_t* __restrict__ xb,
    bf16_t* __restrict__ wqkvT, bf16_t* __restrict__ woutT) {
  __shared__ bf16_t tile[32][33];
  const int bid = blockIdx.x;
  if (bid < 2048) {
    const int i = bid * 256 + threadIdx.x;  // < 524288
    const float4* s = (const float4*)x;
    float4 a = s[i * 2], b = s[i * 2 + 1];
    bf16x8 o;
    o[0] = (bf16_t)a.x; o[1] = (bf16_t)a.y; o[2] = (bf16_t)a.z; o[3] = (bf16_t)a.w;
    o[4] = (bf16_t)b.x; o[5] = (bf16_t)b.y; o[6] = (bf16_t)b.z; o[7] = (bf16_t)b.w;
    ((bf16x8*)xb)[i] = o;
    return;
  }
  const bool isq = bid < 5120;
  const int id = isq ? bid - 2048 : bid - 5120;
  const int C = isq ? 3072 : 1024;
  const int R = 1024;
  const int nbx = isq ? 96 : 32;
  const float* in = isq ? wq : wo;
  bf16_t* out = isq ? wqkvT : woutT;
  const int c0 = (id % nbx) * 32, r0 = (id / nbx) * 32;
  const int tx4 = threadIdx.x & 7;   // col group (4 cols each)
  const int ty = threadIdx.x >> 3;   // row [0,32)
  // read: one float4 per thread (fully coalesced, 16B/lane)
  {
    const float4 ld =
        *(const float4*)&in[(size_t)(r0 + ty) * C + c0 + tx4 * 4];
    tile[ty][tx4 * 4 + 0] = (bf16_t)ld.x;
    tile[ty][tx4 * 4 + 1] = (bf16_t)ld.y;
    tile[ty][tx4 * 4 + 2] = (bf16_t)ld.z;
    tile[ty][tx4 * 4 + 3] = (bf16_t)ld.w;
  }
  __syncthreads();
  // write: one bf16x4 per thread (8B/lane). out row c0+ty, cols r0+tx4*4..
  {
    bf16x4 w;
    w[0] = tile[tx4 * 4 + 0][ty];
    w[1] = tile[tx4 * 4 + 1][ty];
    w[2] = tile[tx4 * 4 + 2][ty];
    w[3] = tile[tx4 * 4 + 3][ty];
    *(bf16x4*)&out[(size_t)(c0 + ty) * R + r0 + tx4 * 4] = w;
  }
}

// ---------------------------------------------------------------------------
// C[M,N] = A[M,K] @ Bt[N,K]^T + bias[N]. bf16 in; OUT_F32 selects store type.
// BM=BN=128, BK=64, 4 waves 2x2. global_load_lds staging with per-lane
// pre-swizzled SOURCE (chunk cs = cl ^ rl), linear LDS dest; ds_read at
// chunk (h*4+quad)^(row&7) -> 2-way bank aliasing (free). 16 K-iters. (R18)
// ---------------------------------------------------------------------------
template <bool OUT_F32>
__global__ __launch_bounds__(256, 3) void gemm_bt_kernel(
    const bf16_t* __restrict__ A, const bf16_t* __restrict__ Bt,
    const float* __restrict__ bias, void* __restrict__ Cv, int M, int N,
    int K) {
  __shared__ __align__(16) bf16_t sA[128 * 64];  // 16 KB
  __shared__ __align__(16) bf16_t sB[128 * 64];  // 16 KB
  const int tid = threadIdx.x;
  const int wave = tid >> 6, lane = tid & 63;
  const int quad = lane >> 4, l16 = lane & 15;
  const int wm = (wave >> 1) * 64, wn = (wave & 1) * 64;
  const int bm = blockIdx.y * 128, bn = blockIdx.x * 128;

  const int rl = lane >> 3, cl = lane & 7;
  const int srow = wave * 32;
  const bf16_t* gA =
      A + (size_t)(bm + srow + rl) * K + (size_t)((cl ^ rl) << 3);
  const bf16_t* gB =
      Bt + (size_t)(bn + srow + rl) * K + (size_t)((cl ^ rl) << 3);
  bf16_t* lA = sA + srow * 64;
  bf16_t* lB = sB + srow * 64;

  f32x4 acc[4][4] = {};

  for (int k0 = 0; k0 < K; k0 += 64) {
    __syncthreads();
#pragma unroll
    for (int c = 0; c < 4; c++) {
      async_copy16(gA + (size_t)(c * 8) * K + k0, lA + c * 512);
      async_copy16(gB + (size_t)(c * 8) * K + k0, lB + c * 512);
    }
    __syncthreads();

#pragma unroll
    for (int h = 0; h < 2; h++) {
      bf16x8 af[4], bfr[4];
#pragma unroll
      for (int i = 0; i < 4; i++) {
        const int row = wm + i * 16 + l16;
        af[i] = *(const bf16x8*)&sA[row * 64 +
                                    (((h * 4 + quad) ^ (row & 7)) << 3)];
      }
#pragma unroll
      for (int j = 0; j < 4; j++) {
        const int row = wn + j * 16 + l16;
        bfr[j] = *(const bf16x8*)&sB[row * 64 +
                                     (((h * 4 + quad) ^ (row & 7)) << 3)];
      }
#pragma unroll
      for (int i = 0; i < 4; i++)
#pragma unroll
        for (int j = 0; j < 4; j++)
          acc[i][j] = __builtin_amdgcn_mfma_f32_16x16x32_bf16(
              af[i], bfr[j], acc[i][j], 0, 0, 0);
    }
  }

#pragma unroll
  for (int j = 0; j < 4; j++) {
    const int col = bn + wn + j * 16 + l16;
    const float bv = bias[col];
#pragma unroll
    for (int i = 0; i < 4; i++) {
#pragma unroll
      for (int r = 0; r < 4; r++) {
        const int row = bm + wm + i * 16 + quad * 4 + r;
        const float v = acc[i][j][r] + bv;
        if (OUT_F32)
          ((float*)Cv)[(size_t)row * N + col] = v;
        else
          ((bf16_t*)Cv)[(size_t)row * N + col] = (bf16_t)v;
      }
    }
  }
}

// ---------------------------------------------------------------------------
// gemm2: BM=64, BN=128, BK=64 (f32 out), R18 swizzle scheme. Grid
// (N/128, M/64) = 512 blocks = 2 blocks/CU. sA 8KB + sB 16KB = 24KB. (R19)
// ---------------------------------------------------------------------------
__global__ __launch_bounds__(256) void gemm_bt64_kernel(
    const bf16_t* __restrict__ A, const bf16_t* __restrict__ Bt,
    const float* __restrict__ bias, float* __restrict__ C, int M, int N,
    int K) {
  __shared__ __align__(16) bf16_t sA[64 * 64];   // 8 KB
  __shared__ __align__(16) bf16_t sB[128 * 64];  // 16 KB
  const int tid = threadIdx.x;
  const int wave = tid >> 6, lane = tid & 63;
  const int quad = lane >> 4, l16 = lane & 15;
  const int wm = (wave >> 1) * 32, wn = (wave & 1) * 64;
  const int bm = blockIdx.y * 64, bn = blockIdx.x * 128;

  const int rl = lane >> 3, cl = lane & 7;
  const bf16_t* gA =
      A + (size_t)(bm + wave * 16 + rl) * K + (size_t)((cl ^ rl) << 3);
  bf16_t* lA = sA + (wave * 16) * 64;
  const bf16_t* gB =
      Bt + (size_t)(bn + wave * 32 + rl) * K + (size_t)((cl ^ rl) << 3);
  bf16_t* lB = sB + (wave * 32) * 64;

  f32x4 acc[2][4] = {};

  for (int k0 = 0; k0 < K; k0 += 64) {
    __syncthreads();
#pragma unroll
    for (int c = 0; c < 2; c++)
      async_copy16(gA + (size_t)(c * 8) * K + k0, lA + c * 512);
#pragma unroll
    for (int c = 0; c < 4; c++)
      async_copy16(gB + (size_t)(c * 8) * K + k0, lB + c * 512);
    __syncthreads();

#pragma unroll
    for (int h = 0; h < 2; h++) {
      bf16x8 af[2], bfr[4];
#pragma unroll
      for (int i = 0; i < 2; i++) {
        const int row = wm + i * 16 + l16;
        af[i] = *(const bf16x8*)&sA[row * 64 +
                                    (((h * 4 + quad) ^ (row & 7)) << 3)];
      }
#pragma unroll
      for (int j = 0; j < 4; j++) {
        const int row = wn + j * 16 + l16;
        bfr[j] = *(const bf16x8*)&sB[row * 64 +
                                     (((h * 4 + quad) ^ (row & 7)) << 3)];
      }
#pragma unroll
      for (int i = 0; i < 2; i++)
#pragma unroll
        for (int j = 0; j < 4; j++)
          acc[i][j] = __builtin_amdgcn_mfma_f32_16x16x32_bf16(
              af[i], bfr[j], acc[i][j], 0, 0, 0);
    }
  }

#pragma unroll
  for (int j = 0; j < 4; j++) {
    const int col = bn + wn + j * 16 + l16;
    const float bv = bias[col];
#pragma unroll
    for (int i = 0; i < 2; i++) {
#pragma unroll
      for (int r = 0; r < 4; r++) {
        const int row = bm + wm + i * 16 + quad * 4 + r;
        C[(size_t)row * N + col] = acc[i][j][r] + bv;
      }
    }
  }
}

#if HAVE_MFMA16
// ---------------------------------------------------------------------------
// R14 attention (proven, frozen): S^T = K@Q^T (16x16x32), P stays in
// registers as the K=16 MFMA A-fragment; O += P@V via mfma_f32_16x16x16.
// Double-buffered sK/sVt, ONE barrier per 64-key tile. Fixed-M softmax.
// sK : (t,d) at t*64 + (((d>>3) ^ (t&7))<<3) + (d&7)        [8 KB/buf]
// sVt: (d,t) at d*64 + (((t>>2) ^ (d&15))<<2) + (t&3)       [8 KB/buf]
// Main loop = full tiles only (branchless); diagonal tile hoisted after.
// Balance: X remapped so each CU's 4 resident blocks have sum(X)==62.
// ---------------------------------------------------------------------------
__global__ __launch_bounds__(256, 4) void attn_kernel(
    const bf16_t* __restrict__ qkv, bf16_t* __restrict__ Y) {
  constexpr int T = 2048, C3 = 3072;
  constexpr float CSC = 0.18033688f;  // 0.125 * log2(e)
  constexpr float MB = 20.0f;
  __shared__ __align__(16) bf16_t sK[2][64 * 64];
  __shared__ __align__(16) bf16_t sVt[2][64 * 64];

  const int tid = threadIdx.x;
  const int wave = tid >> 6, lane = tid & 63;
  const int quad = lane >> 4, l16 = lane & 15;
  const int bh = blockIdx.y;
  // causal-depth balance remap (bijective in bx for each bh):
  const int flip = (bh >> 3) & 1;
  const int vv = ((int)blockIdx.x + ((bh >> 4) & 1) * 8) & 31;
  const int X = flip ? (31 - vv) : vv;
  const int q0 = X * 64;
  const int b = bh >> 4, h = bh & 15;
  const size_t base = (size_t)b * T * C3 + (size_t)h * 64;

  // Q as B-operand: lane n=l16=query, k = quad*8+j
  const int qrow = q0 + wave * 16 + l16;
  const bf16x8 qf0 = *(const bf16x8*)&qkv[base + (size_t)qrow * C3 + quad * 8];
  const bf16x8 qf1 =
      *(const bf16x8*)&qkv[base + (size_t)qrow * C3 + 32 + quad * 8];

  f32x4 o[4] = {};   // O: lane holds rows (query) quad*4+r, col d = n16*16+l16
  f32x4 l4 = {0.f, 0.f, 0.f, 0.f};  // 4 parallel partial-sum chains

  // K staging: (t = tid>>2 key row, seg = tid&3)
  const int t = tid >> 2, seg = tid & 3;
  const bf16_t* gK = &qkv[base + (size_t)t * C3 + 1024 + seg * 16];
  // V staging: (kq = tid>>4 key-quad, dq = tid&15 d-quad)
  const int kq = tid >> 4, dq = tid & 15;
  const bf16_t* gV = &qkv[base + (size_t)(4 * kq) * C3 + 2048 + dq * 4];

  bf16x8 kr0 = *(const bf16x8*)gK;
  bf16x8 kr1 = *(const bf16x8*)(gK + 8);
  bf16x4 vA0 = *(const bf16x4*)gV;
  bf16x4 vA1 = *(const bf16x4*)(gV + C3);
  bf16x4 vA2 = *(const bf16x4*)(gV + 2 * C3);
  bf16x4 vA3 = *(const bf16x4*)(gV + 3 * C3);

  // ---- main loop: tiles 0..X-1, all keys < all queries: branch-free ----
  for (int kt = 0; kt < X; kt++) {
    const int p = kt & 1;
    // stage K (2 b128, swizzled) and V (4 b64, key-quad granules)
    *(bf16x8*)&sK[p][t * 64 + (((2 * seg + 0) ^ (t & 7)) << 3)] = kr0;
    *(bf16x8*)&sK[p][t * 64 + (((2 * seg + 1) ^ (t & 7)) << 3)] = kr1;
#pragma unroll
    for (int i = 0; i < 4; i++) {
      const int d = dq * 4 + i;
      bf16x4 w;
      w[0] = vA0[i]; w[1] = vA1[i]; w[2] = vA2[i]; w[3] = vA3[i];
      *(bf16x4*)&sVt[p][d * 64 + ((kq ^ (d & 15)) << 2)] = w;
    }
    // prefetch next tile (kt+1 <= X always valid); overlaps compute
    {
      const size_t off = (size_t)(kt + 1) * 64 * C3;
      kr0 = *(const bf16x8*)(gK + off);
      kr1 = *(const bf16x8*)(gK + off + 8);
      vA0 = *(const bf16x4*)(gV + off);
      vA1 = *(const bf16x4*)(gV + off + C3);
      vA2 = *(const bf16x4*)(gV + off + 2 * C3);
      vA3 = *(const bf16x4*)(gV + off + 3 * C3);
    }
    __syncthreads();  // single barrier: buf p visible; buf 1-p free

#pragma unroll
    for (int j = 0; j < 4; j++) {
      // S^T j-tile: A = K-frag (lane m=l16 -> key j*16+l16), B = Q-frag
      const int trow = j * 16 + l16;
      bf16x8 kf0 =
          *(const bf16x8*)&sK[p][trow * 64 + ((quad ^ (trow & 7)) << 3)];
      bf16x8 kf1 =
          *(const bf16x8*)&sK[p][trow * 64 + (((4 + quad) ^ (trow & 7)) << 3)];
      f32x4 s2 = {};
      __builtin_amdgcn_s_setprio(1);
      s2 = __builtin_amdgcn_mfma_f32_16x16x32_bf16(kf0, qf0, s2, 0, 0, 0);
      s2 = __builtin_amdgcn_mfma_f32_16x16x32_bf16(kf1, qf1, s2, 0, 0, 0);
      __builtin_amdgcn_s_setprio(0);
#pragma unroll
      for (int r = 0; r < 4; r++) s2[r] = EXP2F(fmaf(s2[r], CSC, -MB));
      l4 += s2;  // 4 parallel chains
      bf16x4 pb;
      pb[0] = (bf16_t)s2[0]; pb[1] = (bf16_t)s2[1];
      pb[2] = (bf16_t)s2[2]; pb[3] = (bf16_t)s2[3];
      union { bf16x4 bv; short4v sv; } u;
      u.bv = pb;
      const short4v pa = u.sv;
      __builtin_amdgcn_s_setprio(1);
#pragma unroll
      for (int n16 = 0; n16 < 4; n16++) {
        const int d = n16 * 16 + l16;
        const short4v vf = *(const short4v*)&sVt[p][d * 64 +
                                                    (((j * 4 + quad) ^ (d & 15))
                                                     << 2)];
        o[n16] =
            __builtin_amdgcn_mfma_f32_16x16x16bf16_1k(pa, vf, o[n16], 0, 0, 0);
      }
      __builtin_amdgcn_s_setprio(0);
    }
  }

  // ---- diagonal tile kt == X (hoisted; j-skip + diag mask) ----
  {
    const int p = X & 1;
    *(bf16x8*)&sK[p][t * 64 + (((2 * seg + 0) ^ (t & 7)) << 3)] = kr0;
    *(bf16x8*)&sK[p][t * 64 + (((2 * seg + 1) ^ (t & 7)) << 3)] = kr1;
#pragma unroll
    for (int i = 0; i < 4; i++) {
      const int d = dq * 4 + i;
      bf16x4 w;
      w[0] = vA0[i]; w[1] = vA1[i]; w[2] = vA2[i]; w[3] = vA3[i];
      *(bf16x4*)&sVt[p][d * 64 + ((kq ^ (d & 15)) << 2)] = w;
    }
    __syncthreads();

#pragma unroll
    for (int j = 0; j < 4; j++) {
      if (j > wave) continue;  // wave-uniform; P would be all-zero
      const int trow = j * 16 + l16;
      bf16x8 kf0 =
          *(const bf16x8*)&sK[p][trow * 64 + ((quad ^ (trow & 7)) << 3)];
      bf16x8 kf1 =
          *(const bf16x8*)&sK[p][trow * 64 + (((4 + quad) ^ (trow & 7)) << 3)];
      f32x4 s2 = {};
      __builtin_amdgcn_s_setprio(1);
      s2 = __builtin_amdgcn_mfma_f32_16x16x32_bf16(kf0, qf0, s2, 0, 0, 0);
      s2 = __builtin_amdgcn_mfma_f32_16x16x32_bf16(kf1, qf1, s2, 0, 0, 0);
      __builtin_amdgcn_s_setprio(0);
      const bool diag = (j == wave);
#pragma unroll
      for (int r = 0; r < 4; r++) {
        float pv = EXP2F(fmaf(s2[r], CSC, -MB));
        if (diag && (quad * 4 + r > l16)) pv = 0.f;
        s2[r] = pv;
      }
      l4 += s2;
      bf16x4 pb;
      pb[0] = (bf16_t)s2[0]; pb[1] = (bf16_t)s2[1];
      pb[2] = (bf16_t)s2[2]; pb[3] = (bf16_t)s2[3];
      union { bf16x4 bv; short4v sv; } u;
      u.bv = pb;
      const short4v pa = u.sv;
      __builtin_amdgcn_s_setprio(1);
#pragma unroll
      for (int n16 = 0; n16 < 4; n16++) {
        const int d = n16 * 16 + l16;
        const short4v vf = *(const short4v*)&sVt[p][d * 64 +
                                                    (((j * 4 + quad) ^ (d & 15))
                                                     << 2)];
        o[n16] =
            __builtin_amdgcn_mfma_f32_16x16x16bf16_1k(pa, vf, o[n16], 0, 0, 0);
      }
      __builtin_amdgcn_s_setprio(0);
    }
  }

  // epilogue: complete l across quads (2 shuffles), redistribute, store
  float l_acc = (l4[0] + l4[1]) + (l4[2] + l4[3]);
  l_acc += __shfl_xor(l_acc, 16);
  l_acc += __shfl_xor(l_acc, 32);
#pragma unroll
  for (int r = 0; r < 4; r++) {
    const float lr = __shfl(l_acc, quad * 4 + r);
    const float inv = 1.0f / lr;
    const int row = q0 + wave * 16 + quad * 4 + r;
#pragma unroll
    for (int n16 = 0; n16 < 4; n16++)
      Y[((size_t)b * T + row) * 1024 + h * 64 + n16 * 16 + l16] =
          (bf16_t)(o[n16][r] * inv);
  }
}
#else
// ---------------------------------------------------------------------------
// Fallback = R10 attention (sP round-trip), with the R12 balance remap.
// ---------------------------------------------------------------------------
__global__ __launch_bounds__(256, 4) void attn_kernel(
    const bf16_t* __restrict__ qkv, bf16_t* __restrict__ Y) {
  constexpr int T = 2048, C3 = 3072;
  constexpr float CSC = 0.18033688f;
  constexpr float MB = 20.0f;
  __shared__ __align__(16) bf16_t sK[64 * 64];
  __shared__ __align__(16) bf16_t sVt[64 * 64];
  __shared__ __align__(16) bf16_t sP[4][16 * 64];

  const int tid = threadIdx.x;
  const int wave = tid >> 6, lane = tid & 63;
  const int quad = lane >> 4, l16 = lane & 15;
  const int bh = blockIdx.y;
  const int flip = (bh >> 3) & 1;
  const int vv = ((int)blockIdx.x + ((bh >> 4) & 1) * 8) & 31;
  const int X = flip ? (31 - vv) : vv;
  const int q0 = X * 64;
  const int b = bh >> 4, h = bh & 15;
  const size_t base = (size_t)b * T * C3 + (size_t)h * 64;

  const int qrow = q0 + wave * 16 + l16;
  const bf16x8 qf0 = *(const bf16x8*)&qkv[base + (size_t)qrow * C3 + quad * 8];
  const bf16x8 qf1 =
      *(const bf16x8*)&qkv[base + (size_t)qrow * C3 + 32 + quad * 8];

  f32x4 o[4] = {};
  float l_i[4] = {0.f, 0.f, 0.f, 0.f};

  const int t = tid >> 2, seg = tid & 3;
  const int tk = t & 7, tg3 = t >> 3;
  const bf16_t* gK = &qkv[base + (size_t)t * C3 + 1024 + seg * 16];
  const bf16_t* gV = &qkv[base + (size_t)t * C3 + 2048 + seg * 16];

  const int ktiles = X + 1;

  bf16x8 kr0 = *(const bf16x8*)gK;
  bf16x8 kr1 = *(const bf16x8*)(gK + 8);
  bf16x8 vr0 = *(const bf16x8*)gV;
  bf16x8 vr1 = *(const bf16x8*)(gV + 8);

  for (int kt = 0; kt < ktiles; kt++) {
    __syncthreads();
    *(bf16x8*)&sK[t * 64 + (((2 * seg + 0) ^ tk) << 3)] = kr0;
    *(bf16x8*)&sK[t * 64 + (((2 * seg + 1) ^ tk) << 3)] = kr1;
#pragma unroll
    for (int i = 0; i < 8; i++) {
      const int d = seg * 16 + i;
      sVt[d * 64 + ((tg3 ^ (d >> 3)) << 3) + (t & 7)] = vr0[i];
    }
#pragma unroll
    for (int i = 0; i < 8; i++) {
      const int d = seg * 16 + 8 + i;
      sVt[d * 64 + ((tg3 ^ (d >> 3)) << 3) + (t & 7)] = vr1[i];
    }
    __syncthreads();

    if (kt + 1 < ktiles) {
      const size_t off = (size_t)(kt + 1) * 64 * C3;
      kr0 = *(const bf16x8*)(gK + off);
      kr1 = *(const bf16x8*)(gK + off + 8);
      vr0 = *(const bf16x8*)(gV + off);
      vr1 = *(const bf16x8*)(gV + off + 8);
    }

    f32x4 s[4] = {};
#pragma unroll
    for (int j = 0; j < 4; j++) {
      const int kkey = l16 & 7;
      bf16x8 kf0 =
          *(const bf16x8*)&sK[(j * 16 + l16) * 64 + ((quad ^ kkey) << 3)];
      bf16x8 kf1 =
          *(const bf16x8*)&sK[(j * 16 + l16) * 64 + (((4 + quad) ^ kkey) << 3)];
      s[j] = __builtin_amdgcn_mfma_f32_16x16x32_bf16(qf0, kf0, s[j], 0, 0, 0);
      s[j] = __builtin_amdgcn_mfma_f32_16x16x32_bf16(qf1, kf1, s[j], 0, 0, 0);
    }

#pragma unroll
    for (int j = 0; j < 4; j++)
#pragma unroll
      for (int r = 0; r < 4; r++) s[j][r] = EXP2F(fmaf(s[j][r], CSC, -MB));
    if (kt == ktiles - 1) {
      const int k0 = kt * 64;
#pragma unroll
      for (int j = 0; j < 4; j++) {
        const int kcol = k0 + j * 16 + l16;
#pragma unroll
        for (int r = 0; r < 4; r++)
          if (kcol > q0 + wave * 16 + quad * 4 + r) s[j][r] = 0.f;
      }
    }
#pragma unroll
    for (int j = 0; j < 4; j++)
#pragma unroll
      for (int r = 0; r < 4; r++) l_i[r] += s[j][r];

    bf16_t* sp = &sP[wave][0];
#pragma unroll
    for (int j = 0; j < 4; j++)
#pragma unroll
      for (int r = 0; r < 4; r++) {
        const int m = quad * 4 + r;
        const int kw = (m + (m >> 3)) & 7;
        sp[m * 64 + ((((2 * j + (l16 >> 3)) ^ kw)) << 3) + (l16 & 7)] =
            (bf16_t)s[j][r];
      }

    const int kap = (l16 + (l16 >> 3)) & 7;
#pragma unroll
    for (int s2 = 0; s2 < 2; s2++) {
      bf16x8 pf =
          *(const bf16x8*)&sp[l16 * 64 + (((4 * s2 + quad) ^ kap) << 3)];
#pragma unroll
      for (int j = 0; j < 4; j++) {
        const int d = j * 16 + l16;
        bf16x8 vf =
            *(const bf16x8*)&sVt[d * 64 + (((4 * s2 + quad) ^ (d >> 3)) << 3)];
        o[j] = __builtin_amdgcn_mfma_f32_16x16x32_bf16(pf, vf, o[j], 0, 0, 0);
      }
    }
  }

#pragma unroll
  for (int r = 0; r < 4; r++) {
    float l = l_i[r];
#pragma unroll
    for (int off = 1; off < 16; off <<= 1) l += __shfl_xor(l, off);
    const float inv = 1.0f / l;
    const int row = q0 + wave * 16 + quad * 4 + r;
#pragma unroll
    for (int j = 0; j < 4; j++)
      Y[((size_t)b * T + row) * 1024 + h * 64 + j * 16 + l16] =
          (bf16_t)(o[j][r] * inv);
  }
}
#endif

// ---------------------------------------------------------------------------
extern "C" void kernel_launch(void* const* d_in, const int* in_sizes, int n_in,
                              void* d_out, int out_size, void* d_ws,
                              size_t ws_size, hipStream_t stream) {
  const float* x = nullptr;
  const float* w_qkv = nullptr;
  const float* b_qkv = nullptr;
  const float* w_out = nullptr;
  const float* b_out = nullptr;
  for (int i = 0; i < n_in; i++) {
    switch (in_sizes[i]) {
      case 4194304: x = (const float*)d_in[i]; break;
      case 3145728: w_qkv = (const float*)d_in[i]; break;
      case 3072:    b_qkv = (const float*)d_in[i]; break;
      case 1048576: w_out = (const float*)d_in[i]; break;
      case 1024:    b_out = (const float*)d_in[i]; break;
      default: break;
    }
  }
  float* out = (float*)d_out;  // FP32 output

  bf16_t* xb = (bf16_t*)d_ws;
  bf16_t* wqkvT = xb + (size_t)4194304;
  bf16_t* woutT = wqkvT + (size_t)3145728;
  bf16_t* qkv = woutT + (size_t)1048576;
  bf16_t* Y = qkv + (size_t)12582912;

  prep_kernel<<<6144, 256, 0, stream>>>(x, w_qkv, w_out, xb, wqkvT, woutT);
  gemm_bt_kernel<false><<<dim3(24, 32), 256, 0, stream>>>(
      xb, wqkvT, b_qkv, (void*)qkv, 4096, 3072, 1024);
  attn_kernel<<<dim3(32, 32), 256, 0, stream>>>(qkv, Y);
  gemm_bt64_kernel<<<dim3(8, 64), 256, 0, stream>>>(
      Y, woutT, b_out, out, 4096, 1024, 1024);
}

// Round 11
// 171.287 us; speedup vs baseline: 1.1415x; 1.0034x over previous
//
#include <hip/hip_runtime.h>
#include <hip/hip_bf16.h>
#include <stdint.h>

// SelfAttention B=2,T=2048,C=1024,H=16,hd=64. Inputs fp32, output fp32.
// R22: attn K-staging -> global_load_lds with pre-swizzled SOURCE (m173
// pattern, proven in this session's gemm1/gemm2). sK swizzle identity:
// slot g^(t&7) holds global chunk g; lane r*8+c of the 8-row call writes
// linear slot c from global chunk c^r (t&7==r). K loads for tile kt+1
// issue right AFTER barrier(kt) into the free buffer -> overlap the full
// compute phase, drain at barrier(kt+1). Removes 2 ds_write_b128 + 2
// global reg-loads per thread per tile from the serial walk; -16 VGPR.
// V staging unchanged (transposed 8B granules can't use gload_lds).
// Work distribution / walk / balance remap / layouts all unchanged.
// gemm1 = R18, gemm2 = R19, prep = R21 (all proven).

typedef __bf16 bf16_t;
typedef __attribute__((ext_vector_type(8))) __bf16 bf16x8;
typedef __attribute__((ext_vector_type(4))) __bf16 bf16x4;
typedef __attribute__((ext_vector_type(4))) short short4v;
typedef __attribute__((ext_vector_type(4))) float f32x4;

static_assert(sizeof(bf16x8) == 16, "bf16x8 must be 16B");

#if defined(__has_builtin)
#if __has_builtin(__builtin_amdgcn_mfma_f32_16x16x16bf16_1k)
#define HAVE_MFMA16 1
#endif
#if __has_builtin(__builtin_amdgcn_exp2f)
#define EXP2F(x) __builtin_amdgcn_exp2f(x)
#endif
#endif
#ifndef HAVE_MFMA16
#define HAVE_MFMA16 0
#endif
#ifndef EXP2F
#define EXP2F(x) exp2f(x)
#endif

// async global->LDS, 16B/lane. LDS dest = wave-uniform base + lane*16.
__device__ inline void async_copy16(const bf16_t* gsrc, bf16_t* lds_dst) {
  __builtin_amdgcn_global_load_lds(
      (const __attribute__((address_space(1))) uint32_t*)(const void*)gsrc,
      (__attribute__((address_space(3))) uint32_t*)(void*)lds_dst,
      16, 0, 0);
}

// ---------------------------------------------------------------------------
// Merged prep: blocks [0,2048) convx; [2048,5120) transpose w_qkv;
// [5120,6144) transpose w_out. Transpose: float4 read, bf16x4 write. (R21)
// ---------------------------------------------------------------------------
__global__ __launch_bounds__(256) void prep_kernel(
    const float* __restrict__ x, const float* __restrict__ wq,
    const float* __restrict__ wo, bf16_t* __restrict__ xb,
    bf16_t* __restrict__ wqkvT, bf16_t* __restrict__ woutT) {
  __shared__ bf16_t tile[32][33];
  const int bid = blockIdx.x;
  if (bid < 2048) {
    const int i = bid * 256 + threadIdx.x;  // < 524288
    const float4* s = (const float4*)x;
    float4 a = s[i * 2], b = s[i * 2 + 1];
    bf16x8 o;
    o[0] = (bf16_t)a.x; o[1] = (bf16_t)a.y; o[2] = (bf16_t)a.z; o[3] = (bf16_t)a.w;
    o[4] = (bf16_t)b.x; o[5] = (bf16_t)b.y; o[6] = (bf16_t)b.z; o[7] = (bf16_t)b.w;
    ((bf16x8*)xb)[i] = o;
    return;
  }
  const bool isq = bid < 5120;
  const int id = isq ? bid - 2048 : bid - 5120;
  const int C = isq ? 3072 : 1024;
  const int R = 1024;
  const int nbx = isq ? 96 : 32;
  const float* in = isq ? wq : wo;
  bf16_t* out = isq ? wqkvT : woutT;
  const int c0 = (id % nbx) * 32, r0 = (id / nbx) * 32;
  const int tx4 = threadIdx.x & 7;   // col group (4 cols each)
  const int ty = threadIdx.x >> 3;   // row [0,32)
  {
    const float4 ld =
        *(const float4*)&in[(size_t)(r0 + ty) * C + c0 + tx4 * 4];
    tile[ty][tx4 * 4 + 0] = (bf16_t)ld.x;
    tile[ty][tx4 * 4 + 1] = (bf16_t)ld.y;
    tile[ty][tx4 * 4 + 2] = (bf16_t)ld.z;
    tile[ty][tx4 * 4 + 3] = (bf16_t)ld.w;
  }
  __syncthreads();
  {
    bf16x4 w;
    w[0] = tile[tx4 * 4 + 0][ty];
    w[1] = tile[tx4 * 4 + 1][ty];
    w[2] = tile[tx4 * 4 + 2][ty];
    w[3] = tile[tx4 * 4 + 3][ty];
    *(bf16x4*)&out[(size_t)(c0 + ty) * R + r0 + tx4 * 4] = w;
  }
}

// ---------------------------------------------------------------------------
// C[M,N] = A[M,K] @ Bt[N,K]^T + bias[N]. bf16 in; OUT_F32 selects store type.
// BM=BN=128, BK=64, 4 waves 2x2. global_load_lds staging with per-lane
// pre-swizzled SOURCE (chunk cs = cl ^ rl), linear LDS dest; ds_read at
// chunk (h*4+quad)^(row&7) -> 2-way bank aliasing (free). 16 K-iters. (R18)
// ---------------------------------------------------------------------------
template <bool OUT_F32>
__global__ __launch_bounds__(256, 3) void gemm_bt_kernel(
    const bf16_t* __restrict__ A, const bf16_t* __restrict__ Bt,
    const float* __restrict__ bias, void* __restrict__ Cv, int M, int N,
    int K) {
  __shared__ __align__(16) bf16_t sA[128 * 64];  // 16 KB
  __shared__ __align__(16) bf16_t sB[128 * 64];  // 16 KB
  const int tid = threadIdx.x;
  const int wave = tid >> 6, lane = tid & 63;
  const int quad = lane >> 4, l16 = lane & 15;
  const int wm = (wave >> 1) * 64, wn = (wave & 1) * 64;
  const int bm = blockIdx.y * 128, bn = blockIdx.x * 128;

  const int rl = lane >> 3, cl = lane & 7;
  const int srow = wave * 32;
  const bf16_t* gA =
      A + (size_t)(bm + srow + rl) * K + (size_t)((cl ^ rl) << 3);
  const bf16_t* gB =
      Bt + (size_t)(bn + srow + rl) * K + (size_t)((cl ^ rl) << 3);
  bf16_t* lA = sA + srow * 64;
  bf16_t* lB = sB + srow * 64;

  f32x4 acc[4][4] = {};

  for (int k0 = 0; k0 < K; k0 += 64) {
    __syncthreads();
#pragma unroll
    for (int c = 0; c < 4; c++) {
      async_copy16(gA + (size_t)(c * 8) * K + k0, lA + c * 512);
      async_copy16(gB + (size_t)(c * 8) * K + k0, lB + c * 512);
    }
    __syncthreads();

#pragma unroll
    for (int h = 0; h < 2; h++) {
      bf16x8 af[4], bfr[4];
#pragma unroll
      for (int i = 0; i < 4; i++) {
        const int row = wm + i * 16 + l16;
        af[i] = *(const bf16x8*)&sA[row * 64 +
                                    (((h * 4 + quad) ^ (row & 7)) << 3)];
      }
#pragma unroll
      for (int j = 0; j < 4; j++) {
        const int row = wn + j * 16 + l16;
        bfr[j] = *(const bf16x8*)&sB[row * 64 +
                                     (((h * 4 + quad) ^ (row & 7)) << 3)];
      }
#pragma unroll
      for (int i = 0; i < 4; i++)
#pragma unroll
        for (int j = 0; j < 4; j++)
          acc[i][j] = __builtin_amdgcn_mfma_f32_16x16x32_bf16(
              af[i], bfr[j], acc[i][j], 0, 0, 0);
    }
  }

#pragma unroll
  for (int j = 0; j < 4; j++) {
    const int col = bn + wn + j * 16 + l16;
    const float bv = bias[col];
#pragma unroll
    for (int i = 0; i < 4; i++) {
#pragma unroll
      for (int r = 0; r < 4; r++) {
        const int row = bm + wm + i * 16 + quad * 4 + r;
        const float v = acc[i][j][r] + bv;
        if (OUT_F32)
          ((float*)Cv)[(size_t)row * N + col] = v;
        else
          ((bf16_t*)Cv)[(size_t)row * N + col] = (bf16_t)v;
      }
    }
  }
}

// ---------------------------------------------------------------------------
// gemm2: BM=64, BN=128, BK=64 (f32 out), R18 swizzle scheme. Grid
// (N/128, M/64) = 512 blocks = 2 blocks/CU. sA 8KB + sB 16KB = 24KB. (R19)
// ---------------------------------------------------------------------------
__global__ __launch_bounds__(256) void gemm_bt64_kernel(
    const bf16_t* __restrict__ A, const bf16_t* __restrict__ Bt,
    const float* __restrict__ bias, float* __restrict__ C, int M, int N,
    int K) {
  __shared__ __align__(16) bf16_t sA[64 * 64];   // 8 KB
  __shared__ __align__(16) bf16_t sB[128 * 64];  // 16 KB
  const int tid = threadIdx.x;
  const int wave = tid >> 6, lane = tid & 63;
  const int quad = lane >> 4, l16 = lane & 15;
  const int wm = (wave >> 1) * 32, wn = (wave & 1) * 64;
  const int bm = blockIdx.y * 64, bn = blockIdx.x * 128;

  const int rl = lane >> 3, cl = lane & 7;
  const bf16_t* gA =
      A + (size_t)(bm + wave * 16 + rl) * K + (size_t)((cl ^ rl) << 3);
  bf16_t* lA = sA + (wave * 16) * 64;
  const bf16_t* gB =
      Bt + (size_t)(bn + wave * 32 + rl) * K + (size_t)((cl ^ rl) << 3);
  bf16_t* lB = sB + (wave * 32) * 64;

  f32x4 acc[2][4] = {};

  for (int k0 = 0; k0 < K; k0 += 64) {
    __syncthreads();
#pragma unroll
    for (int c = 0; c < 2; c++)
      async_copy16(gA + (size_t)(c * 8) * K + k0, lA + c * 512);
#pragma unroll
    for (int c = 0; c < 4; c++)
      async_copy16(gB + (size_t)(c * 8) * K + k0, lB + c * 512);
    __syncthreads();

#pragma unroll
    for (int h = 0; h < 2; h++) {
      bf16x8 af[2], bfr[4];
#pragma unroll
      for (int i = 0; i < 2; i++) {
        const int row = wm + i * 16 + l16;
        af[i] = *(const bf16x8*)&sA[row * 64 +
                                    (((h * 4 + quad) ^ (row & 7)) << 3)];
      }
#pragma unroll
      for (int j = 0; j < 4; j++) {
        const int row = wn + j * 16 + l16;
        bfr[j] = *(const bf16x8*)&sB[row * 64 +
                                     (((h * 4 + quad) ^ (row & 7)) << 3)];
      }
#pragma unroll
      for (int i = 0; i < 2; i++)
#pragma unroll
        for (int j = 0; j < 4; j++)
          acc[i][j] = __builtin_amdgcn_mfma_f32_16x16x32_bf16(
              af[i], bfr[j], acc[i][j], 0, 0, 0);
    }
  }

#pragma unroll
  for (int j = 0; j < 4; j++) {
    const int col = bn + wn + j * 16 + l16;
    const float bv = bias[col];
#pragma unroll
    for (int i = 0; i < 2; i++) {
#pragma unroll
      for (int r = 0; r < 4; r++) {
        const int row = bm + wm + i * 16 + quad * 4 + r;
        C[(size_t)row * N + col] = acc[i][j][r] + bv;
      }
    }
  }
}

#if HAVE_MFMA16
// ---------------------------------------------------------------------------
// R22 attention = R14 structure with K staged via global_load_lds.
// S^T = K@Q^T (16x16x32), P in registers as the K=16 MFMA A-fragment;
// O += P@V via mfma_f32_16x16x16. Double-buffered sK/sVt, ONE barrier per
// 64-key tile. Fixed-M softmax. Main loop branchless; diag hoisted.
// sK : (t,d) slot g^(t&7) holds global chunk g       [8 KB/buf]
//      staged: lane r*8+c of 8-row call writes linear slot c from global
//      chunk c^r (t&7 == r) -> identical layout, no reg round-trip.
// sVt: (d,t) at d*64 + ((kq ^ (d&15))<<2)            [8 KB/buf, reg path]
// K loads for tile kt+1 issue AFTER barrier(kt) into the free buffer
// (readers of it finished before the barrier) and drain at barrier(kt+1).
// Balance: X remapped so each CU's 4 resident blocks have sum(X)==62.
// ---------------------------------------------------------------------------
__global__ __launch_bounds__(256, 4) void attn_kernel(
    const bf16_t* __restrict__ qkv, bf16_t* __restrict__ Y) {
  constexpr int T = 2048, C3 = 3072;
  constexpr float CSC = 0.18033688f;  // 0.125 * log2(e)
  constexpr float MB = 20.0f;
  __shared__ __align__(16) bf16_t sK[2][64 * 64];
  __shared__ __align__(16) bf16_t sVt[2][64 * 64];

  const int tid = threadIdx.x;
  const int wave = tid >> 6, lane = tid & 63;
  const int quad = lane >> 4, l16 = lane & 15;
  const int bh = blockIdx.y;
  // causal-depth balance remap (bijective in bx for each bh):
  const int flip = (bh >> 3) & 1;
  const int vv = ((int)blockIdx.x + ((bh >> 4) & 1) * 8) & 31;
  const int X = flip ? (31 - vv) : vv;
  const int q0 = X * 64;
  const int b = bh >> 4, h = bh & 15;
  const size_t base = (size_t)b * T * C3 + (size_t)h * 64;

  // Q as B-operand: lane n=l16=query, k = quad*8+j
  const int qrow = q0 + wave * 16 + l16;
  const bf16x8 qf0 = *(const bf16x8*)&qkv[base + (size_t)qrow * C3 + quad * 8];
  const bf16x8 qf1 =
      *(const bf16x8*)&qkv[base + (size_t)qrow * C3 + 32 + quad * 8];

  f32x4 o[4] = {};   // O: lane holds rows (query) quad*4+r, col d = n16*16+l16
  f32x4 l4 = {0.f, 0.f, 0.f, 0.f};  // 4 parallel partial-sum chains

  // K staging via gload_lds: wave covers key rows [16w,16w+16), 2 calls x
  // 8 rows. lane r*8+c -> LDS row 16w+8q+r slot c, source chunk c^r.
  const int krr = lane >> 3, kcc = lane & 7;
  const bf16_t* gKa =
      &qkv[base + (size_t)(16 * wave + krr) * C3 + 1024 + ((kcc ^ krr) << 3)];
  bf16_t* const lK0 = (bf16_t*)&sK[0][(16 * wave) * 64];
  bf16_t* const lK1 = (bf16_t*)&sK[1][(16 * wave) * 64];

  // V staging: (kq = tid>>4 key-quad, dq = tid&15 d-quad), reg path
  const int kq = tid >> 4, dq = tid & 15;
  const bf16_t* gV = &qkv[base + (size_t)(4 * kq) * C3 + 2048 + dq * 4];

  // prologue: issue tile-0 K loads; prefetch tile-0 V regs
  async_copy16(gKa, lK0);
  async_copy16(gKa + (size_t)8 * C3, lK0 + 8 * 64);
  bf16x4 vA0 = *(const bf16x4*)gV;
  bf16x4 vA1 = *(const bf16x4*)(gV + C3);
  bf16x4 vA2 = *(const bf16x4*)(gV + 2 * C3);
  bf16x4 vA3 = *(const bf16x4*)(gV + 3 * C3);

  // ---- main loop: tiles 0..X-1, all keys < all queries: branch-free ----
  for (int kt = 0; kt < X; kt++) {
    const int p = kt & 1;
    // stage V (4 b64, key-quad granules)
#pragma unroll
    for (int i = 0; i < 4; i++) {
      const int d = dq * 4 + i;
      bf16x4 w;
      w[0] = vA0[i]; w[1] = vA1[i]; w[2] = vA2[i]; w[3] = vA3[i];
      *(bf16x4*)&sVt[p][d * 64 + ((kq ^ (d & 15)) << 2)] = w;
    }
    // prefetch next V tile (kt+1 <= X always valid); overlaps compute
    {
      const size_t off = (size_t)(kt + 1) * 64 * C3;
      vA0 = *(const bf16x4*)(gV + off);
      vA1 = *(const bf16x4*)(gV + off + C3);
      vA2 = *(const bf16x4*)(gV + off + 2 * C3);
      vA3 = *(const bf16x4*)(gV + off + 3 * C3);
    }
    __syncthreads();  // drains K gload_lds(kt) + sVt[p] visible + buf 1-p free

    // issue K loads for tile kt+1 into the now-free buffer; they overlap
    // the whole compute phase and drain at the next barrier.
    {
      const size_t off = (size_t)(kt + 1) * 64 * C3;
      bf16_t* const lKn = p ? lK0 : lK1;
      async_copy16(gKa + off, lKn);
      async_copy16(gKa + off + (size_t)8 * C3, lKn + 8 * 64);
    }

#pragma unroll
    for (int j = 0; j < 4; j++) {
      // S^T j-tile: A = K-frag (lane m=l16 -> key j*16+l16), B = Q-frag
      const int trow = j * 16 + l16;
      bf16x8 kf0 =
          *(const bf16x8*)&sK[p][trow * 64 + ((quad ^ (trow & 7)) << 3)];
      bf16x8 kf1 =
          *(const bf16x8*)&sK[p][trow * 64 + (((4 + quad) ^ (trow & 7)) << 3)];
      f32x4 s2 = {};
      __builtin_amdgcn_s_setprio(1);
      s2 = __builtin_amdgcn_mfma_f32_16x16x32_bf16(kf0, qf0, s2, 0, 0, 0);
      s2 = __builtin_amdgcn_mfma_f32_16x16x32_bf16(kf1, qf1, s2, 0, 0, 0);
      __builtin_amdgcn_s_setprio(0);
#pragma unroll
      for (int r = 0; r < 4; r++) s2[r] = EXP2F(fmaf(s2[r], CSC, -MB));
      l4 += s2;  // 4 parallel chains
      bf16x4 pb;
      pb[0] = (bf16_t)s2[0]; pb[1] = (bf16_t)s2[1];
      pb[2] = (bf16_t)s2[2]; pb[3] = (bf16_t)s2[3];
      union { bf16x4 bv; short4v sv; } u;
      u.bv = pb;
      const short4v pa = u.sv;
      __builtin_amdgcn_s_setprio(1);
#pragma unroll
      for (int n16 = 0; n16 < 4; n16++) {
        const int d = n16 * 16 + l16;
        const short4v vf = *(const short4v*)&sVt[p][d * 64 +
                                                    (((j * 4 + quad) ^ (d & 15))
                                                     << 2)];
        o[n16] =
            __builtin_amdgcn_mfma_f32_16x16x16bf16_1k(pa, vf, o[n16], 0, 0, 0);
      }
      __builtin_amdgcn_s_setprio(0);
    }
  }

  // ---- diagonal tile kt == X (hoisted; j-skip + diag mask). K for this
  // tile was issued at iter X-1 (or the prologue when X==0). ----
  {
    const int p = X & 1;
#pragma unroll
    for (int i = 0; i < 4; i++) {
      const int d = dq * 4 + i;
      bf16x4 w;
      w[0] = vA0[i]; w[1] = vA1[i]; w[2] = vA2[i]; w[3] = vA3[i];
      *(bf16x4*)&sVt[p][d * 64 + ((kq ^ (d & 15)) << 2)] = w;
    }
    __syncthreads();  // drains K gload_lds(X); sVt[p] visible

#pragma unroll
    for (int j = 0; j < 4; j++) {
      if (j > wave) continue;  // wave-uniform; P would be all-zero
      const int trow = j * 16 + l16;
      bf16x8 kf0 =
          *(const bf16x8*)&sK[p][trow * 64 + ((quad ^ (trow & 7)) << 3)];
      bf16x8 kf1 =
          *(const bf16x8*)&sK[p][trow * 64 + (((4 + quad) ^ (trow & 7)) << 3)];
      f32x4 s2 = {};
      __builtin_amdgcn_s_setprio(1);
      s2 = __builtin_amdgcn_mfma_f32_16x16x32_bf16(kf0, qf0, s2, 0, 0, 0);
      s2 = __builtin_amdgcn_mfma_f32_16x16x32_bf16(kf1, qf1, s2, 0, 0, 0);
      __builtin_amdgcn_s_setprio(0);
      const bool diag = (j == wave);
#pragma unroll
      for (int r = 0; r < 4; r++) {
        float pv = EXP2F(fmaf(s2[r], CSC, -MB));
        if (diag && (quad * 4 + r > l16)) pv = 0.f;
        s2[r] = pv;
      }
      l4 += s2;
      bf16x4 pb;
      pb[0] = (bf16_t)s2[0]; pb[1] = (bf16_t)s2[1];
      pb[2] = (bf16_t)s2[2]; pb[3] = (bf16_t)s2[3];
      union { bf16x4 bv; short4v sv; } u;
      u.bv = pb;
      const short4v pa = u.sv;
      __builtin_amdgcn_s_setprio(1);
#pragma unroll
      for (int n16 = 0; n16 < 4; n16++) {
        const int d = n16 * 16 + l16;
        const short4v vf = *(const short4v*)&sVt[p][d * 64 +
                                                    (((j * 4 + quad) ^ (d & 15))
                                                     << 2)];
        o[n16] =
            __builtin_amdgcn_mfma_f32_16x16x16bf16_1k(pa, vf, o[n16], 0, 0, 0);
      }
      __builtin_amdgcn_s_setprio(0);
    }
  }

  // epilogue: complete l across quads (2 shuffles), redistribute, store
  float l_acc = (l4[0] + l4[1]) + (l4[2] + l4[3]);
  l_acc += __shfl_xor(l_acc, 16);
  l_acc += __shfl_xor(l_acc, 32);
#pragma unroll
  for (int r = 0; r < 4; r++) {
    const float lr = __shfl(l_acc, quad * 4 + r);
    const float inv = 1.0f / lr;
    const int row = q0 + wave * 16 + quad * 4 + r;
#pragma unroll
    for (int n16 = 0; n16 < 4; n16++)
      Y[((size_t)b * T + row) * 1024 + h * 64 + n16 * 16 + l16] =
          (bf16_t)(o[n16][r] * inv);
  }
}
#else
// ---------------------------------------------------------------------------
// Fallback = R10 attention (sP round-trip), with the R12 balance remap.
// ---------------------------------------------------------------------------
__global__ __launch_bounds__(256, 4) void attn_kernel(
    const bf16_t* __restrict__ qkv, bf16_t* __restrict__ Y) {
  constexpr int T = 2048, C3 = 3072;
  constexpr float CSC = 0.18033688f;
  constexpr float MB = 20.0f;
  __shared__ __align__(16) bf16_t sK[64 * 64];
  __shared__ __align__(16) bf16_t sVt[64 * 64];
  __shared__ __align__(16) bf16_t sP[4][16 * 64];

  const int tid = threadIdx.x;
  const int wave = tid >> 6, lane = tid & 63;
  const int quad = lane >> 4, l16 = lane & 15;
  const int bh = blockIdx.y;
  const int flip = (bh >> 3) & 1;
  const int vv = ((int)blockIdx.x + ((bh >> 4) & 1) * 8) & 31;
  const int X = flip ? (31 - vv) : vv;
  const int q0 = X * 64;
  const int b = bh >> 4, h = bh & 15;
  const size_t base = (size_t)b * T * C3 + (size_t)h * 64;

  const int qrow = q0 + wave * 16 + l16;
  const bf16x8 qf0 = *(const bf16x8*)&qkv[base + (size_t)qrow * C3 + quad * 8];
  const bf16x8 qf1 =
      *(const bf16x8*)&qkv[base + (size_t)qrow * C3 + 32 + quad * 8];

  f32x4 o[4] = {};
  float l_i[4] = {0.f, 0.f, 0.f, 0.f};

  const int t = tid >> 2, seg = tid & 3;
  const int tk = t & 7, tg3 = t >> 3;
  const bf16_t* gK = &qkv[base + (size_t)t * C3 + 1024 + seg * 16];
  const bf16_t* gV = &qkv[base + (size_t)t * C3 + 2048 + seg * 16];

  const int ktiles = X + 1;

  bf16x8 kr0 = *(const bf16x8*)gK;
  bf16x8 kr1 = *(const bf16x8*)(gK + 8);
  bf16x8 vr0 = *(const bf16x8*)gV;
  bf16x8 vr1 = *(const bf16x8*)(gV + 8);

  for (int kt = 0; kt < ktiles; kt++) {
    __syncthreads();
    *(bf16x8*)&sK[t * 64 + (((2 * seg + 0) ^ tk) << 3)] = kr0;
    *(bf16x8*)&sK[t * 64 + (((2 * seg + 1) ^ tk) << 3)] = kr1;
#pragma unroll
    for (int i = 0; i < 8; i++) {
      const int d = seg * 16 + i;
      sVt[d * 64 + ((tg3 ^ (d >> 3)) << 3) + (t & 7)] = vr0[i];
    }
#pragma unroll
    for (int i = 0; i < 8; i++) {
      const int d = seg * 16 + 8 + i;
      sVt[d * 64 + ((tg3 ^ (d >> 3)) << 3) + (t & 7)] = vr1[i];
    }
    __syncthreads();

    if (kt + 1 < ktiles) {
      const size_t off = (size_t)(kt + 1) * 64 * C3;
      kr0 = *(const bf16x8*)(gK + off);
      kr1 = *(const bf16x8*)(gK + off + 8);
      vr0 = *(const bf16x8*)(gV + off);
      vr1 = *(const bf16x8*)(gV + off + 8);
    }

    f32x4 s[4] = {};
#pragma unroll
    for (int j = 0; j < 4; j++) {
      const int kkey = l16 & 7;
      bf16x8 kf0 =
          *(const bf16x8*)&sK[(j * 16 + l16) * 64 + ((quad ^ kkey) << 3)];
      bf16x8 kf1 =
          *(const bf16x8*)&sK[(j * 16 + l16) * 64 + (((4 + quad) ^ kkey) << 3)];
      s[j] = __builtin_amdgcn_mfma_f32_16x16x32_bf16(qf0, kf0, s[j], 0, 0, 0);
      s[j] = __builtin_amdgcn_mfma_f32_16x16x32_bf16(qf1, kf1, s[j], 0, 0, 0);
    }

#pragma unroll
    for (int j = 0; j < 4; j++)
#pragma unroll
      for (int r = 0; r < 4; r++) s[j][r] = EXP2F(fmaf(s[j][r], CSC, -MB));
    if (kt == ktiles - 1) {
      const int k0 = kt * 64;
#pragma unroll
      for (int j = 0; j < 4; j++) {
        const int kcol = k0 + j * 16 + l16;
#pragma unroll
        for (int r = 0; r < 4; r++)
          if (kcol > q0 + wave * 16 + quad * 4 + r) s[j][r] = 0.f;
      }
    }
#pragma unroll
    for (int j = 0; j < 4; j++)
#pragma unroll
      for (int r = 0; r < 4; r++) l_i[r] += s[j][r];

    bf16_t* sp = &sP[wave][0];
#pragma unroll
    for (int j = 0; j < 4; j++)
#pragma unroll
      for (int r = 0; r < 4; r++) {
        const int m = quad * 4 + r;
        const int kw = (m + (m >> 3)) & 7;
        sp[m * 64 + ((((2 * j + (l16 >> 3)) ^ kw)) << 3) + (l16 & 7)] =
            (bf16_t)s[j][r];
      }

    const int kap = (l16 + (l16 >> 3)) & 7;
#pragma unroll
    for (int s2 = 0; s2 < 2; s2++) {
      bf16x8 pf =
          *(const bf16x8*)&sp[l16 * 64 + (((4 * s2 + quad) ^ kap) << 3)];
#pragma unroll
      for (int j = 0; j < 4; j++) {
        const int d = j * 16 + l16;
        bf16x8 vf =
            *(const bf16x8*)&sVt[d * 64 + (((4 * s2 + quad) ^ (d >> 3)) << 3)];
        o[j] = __builtin_amdgcn_mfma_f32_16x16x32_bf16(pf, vf, o[j], 0, 0, 0);
      }
    }
  }

#pragma unroll
  for (int r = 0; r < 4; r++) {
    float l = l_i[r];
#pragma unroll
    for (int off = 1; off < 16; off <<= 1) l += __shfl_xor(l, off);
    const float inv = 1.0f / l;
    const int row = q0 + wave * 16 + quad * 4 + r;
#pragma unroll
    for (int j = 0; j < 4; j++)
      Y[((size_t)b * T + row) * 1024 + h * 64 + j * 16 + l16] =
          (bf16_t)(o[j][r] * inv);
  }
}
#endif

// ---------------------------------------------------------------------------
extern "C" void kernel_launch(void* const* d_in, const int* in_sizes, int n_in,
                              void* d_out, int out_size, void* d_ws,
                              size_t ws_size, hipStream_t stream) {
  const float* x = nullptr;
  const float* w_qkv = nullptr;
  const float* b_qkv = nullptr;
  const float* w_out = nullptr;
  const float* b_out = nullptr;
  for (int i = 0; i < n_in; i++) {
    switch (in_sizes[i]) {
      case 4194304: x = (const float*)d_in[i]; break;
      case 3145728: w_qkv = (const float*)d_in[i]; break;
      case 3072:    b_qkv = (const float*)d_in[i]; break;
      case 1048576: w_out = (const float*)d_in[i]; break;
      case 1024:    b_out = (const float*)d_in[i]; break;
      default: break;
    }
  }
  float* out = (float*)d_out;  // FP32 output

  bf16_t* xb = (bf16_t*)d_ws;
  bf16_t* wqkvT = xb + (size_t)4194304;
  bf16_t* woutT = wqkvT + (size_t)3145728;
  bf16_t* qkv = woutT + (size_t)1048576;
  bf16_t* Y = qkv + (size_t)12582912;

  prep_kernel<<<6144, 256, 0, stream>>>(x, w_qkv, w_out, xb, wqkvT, woutT);
  gemm_bt_kernel<false><<<dim3(24, 32), 256, 0, stream>>>(
      xb, wqkvT, b_qkv, (void*)qkv, 4096, 3072, 1024);
  attn_kernel<<<dim3(32, 32), 256, 0, stream>>>(qkv, Y);
  gemm_bt64_kernel<<<dim3(8, 64), 256, 0, stream>>>(
      Y, woutT, b_out, out, 4096, 1024, 1024);
}